// Round 1
// baseline (986.986 us; speedup 1.0000x reference)
//
#include <hip/hip_runtime.h>
#include <hip/hip_bf16.h>
#include <math.h>

// BatchTreeEncoder: BS=32, A=4, D=6, H=E=256, V=50000
// LEVEL_SIZES = [32,128,512,2048,8192,32768,131072]
// OFFSETS     = [0,32,160,672,2720,10912,43680,174752]
//
// Only rows j%4==3 of levels>=1 are consumed downstream. Compact index i:
// level-d row j=4i+3 (d>=1), j=i (d=0). Level-d row i reads Hs_{d+1}[i] where
// Hs_{d+1}[i'] = h_{d+1} compact row 4i'+3 (= raw row 16i'+15). Final max is
// fused via atomicMax (int view, out init 0 == relu floor).

__device__ __forceinline__ float sigmoidf_(float x) { return 1.0f / (1.0f + expf(-x)); }

__global__ void prep_transpose(const float* __restrict__ wih, const float* __restrict__ whh,
                               float* __restrict__ wtih, float* __restrict__ wthh) {
  int tid = blockIdx.x * blockDim.x + threadIdx.x; // 0..393215
  int m = tid >= 196608;
  int idx = tid - m * 196608;
  int c = idx % 768;
  int k = idx / 768;
  const float* src = m ? whh : wih;
  float* dst = m ? wthh : wtih;
  dst[idx] = src[c * 256 + k]; // WT[k][c] = W[c][k]
}

__global__ void u0_kernel(const float* __restrict__ sb, const float* __restrict__ cw,
                          float* __restrict__ u0p) {
  int lane = threadIdx.x; // 64 threads
  float s = 0.f;
  #pragma unroll
  for (int q = 0; q < 4; ++q) { int k = lane + 64 * q; s += tanhf(sb[k]) * cw[k]; }
  #pragma unroll
  for (int off = 32; off >= 1; off >>= 1) s += __shfl_xor(s, off);
  if (lane == 0) u0p[0] = tanhf(s);
}

// 16 rows per block, 256 threads. Thread t owns output column t (gi/gh cols t, t+256, t+512).
template <bool FIRST, bool ROOT>
__global__ __launch_bounds__(256)
void level_kernel(const int* __restrict__ tokens,   // pre-offset to level start
                  const float* __restrict__ emb,
                  const float* __restrict__ wtih,   // [256][768] transposed
                  const float* __restrict__ wthh,
                  const float* __restrict__ bih,
                  const float* __restrict__ bhh,
                  const float* __restrict__ sw,     // [256][256] (h,k) row-major
                  const float* __restrict__ sb,     // [256]
                  const float* __restrict__ cw,     // [256]
                  const float* __restrict__ u0p,
                  const float* __restrict__ Hnext,  // [n_rows][256], indexed by compact i
                  float* __restrict__ Hout,
                  int* __restrict__ outI,           // d_out as int for atomicMax
                  float logSm1, int bshift, int bgrp, int store_mode) {
  __shared__ float xs[16][256];
  __shared__ float hs[FIRST ? 1 : 16][256];
  __shared__ float scales[16];

  const int t = threadIdx.x;
  const int i0 = blockIdx.x * 16;

  // ---- stage x (embedding gather) and h_last rows into LDS ----
  {
    int r = t >> 4, c16 = t & 15;
    int i = i0 + r;
    int tok = tokens[ROOT ? i : (4 * i + 3)];
    const float4* src = (const float4*)(emb + (size_t)tok * 256);
    float4* dx = (float4*)xs[r];
    #pragma unroll
    for (int q = 0; q < 4; ++q) dx[c16 + 16 * q] = src[c16 + 16 * q];
    if constexpr (!FIRST) {
      const float4* hsrc = (const float4*)(Hnext + (size_t)i * 256);
      float4* dh = (float4*)hs[r];
      #pragma unroll
      for (int q = 0; q < 4; ++q) dh[c16 + 16 * q] = hsrc[c16 + 16 * q];
    }
  }
  __syncthreads();

  // ---- attention scale per row (wave w handles rows 4w..4w+3, all 256 k) ----
  if constexpr (!FIRST) {
    int wid = t >> 6, lane = t & 63;
    float acc[4][4];
    #pragma unroll
    for (int rr = 0; rr < 4; ++rr)
      #pragma unroll
      for (int q = 0; q < 4; ++q) acc[rr][q] = 0.f;
    for (int h4 = 0; h4 < 64; ++h4) {
      float4 hv[4];
      #pragma unroll
      for (int rr = 0; rr < 4; ++rr) hv[rr] = ((const float4*)hs[4 * wid + rr])[h4];
      #pragma unroll
      for (int kk = 0; kk < 4; ++kk) {
        #pragma unroll
        for (int q = 0; q < 4; ++q) {
          float swv = sw[(4 * h4 + kk) * 256 + lane + 64 * q];
          #pragma unroll
          for (int rr = 0; rr < 4; ++rr) acc[rr][q] += (&hv[rr].x)[kk] * swv;
        }
      }
    }
    float u0v = u0p[0];
    #pragma unroll
    for (int rr = 0; rr < 4; ++rr) {
      float s = 0.f;
      #pragma unroll
      for (int q = 0; q < 4; ++q) {
        int k = lane + 64 * q;
        s += tanhf(acc[rr][q] + sb[k]) * cw[k];
      }
      #pragma unroll
      for (int off = 32; off >= 1; off >>= 1) s += __shfl_xor(s, off);
      if (lane == 0) {
        float v = tanhf(s);
        scales[4 * wid + rr] = sigmoidf_(v - u0v - logSm1);
      }
    }
    __syncthreads();
  }

  // ---- GRU GEMMs: gi = X@Wih^T, gh_mat = Hlast@Whh^T (scale folded in later) ----
  float ai0[16], ai1[16], ai2[16];
  float ah0[16], ah1[16], ah2[16];
  #pragma unroll
  for (int r = 0; r < 16; ++r) {
    ai0[r] = ai1[r] = ai2[r] = 0.f;
    if constexpr (!FIRST) { ah0[r] = ah1[r] = ah2[r] = 0.f; }
  }

  for (int kb = 0; kb < 64; ++kb) {
    float wi[3][4], wh[3][4];
    #pragma unroll
    for (int kk = 0; kk < 4; ++kk) {
      int rowoff = (4 * kb + kk) * 768 + t;
      #pragma unroll
      for (int p = 0; p < 3; ++p) {
        wi[p][kk] = wtih[rowoff + p * 256];
        if constexpr (!FIRST) wh[p][kk] = wthh[rowoff + p * 256];
      }
    }
    #pragma unroll
    for (int r = 0; r < 16; ++r) {
      float4 xv = ((const float4*)xs[r])[kb];
      ai0[r] += xv.x * wi[0][0] + xv.y * wi[0][1] + xv.z * wi[0][2] + xv.w * wi[0][3];
      ai1[r] += xv.x * wi[1][0] + xv.y * wi[1][1] + xv.z * wi[1][2] + xv.w * wi[1][3];
      ai2[r] += xv.x * wi[2][0] + xv.y * wi[2][1] + xv.z * wi[2][2] + xv.w * wi[2][3];
      if constexpr (!FIRST) {
        float4 hv = ((const float4*)hs[r])[kb];
        ah0[r] += hv.x * wh[0][0] + hv.y * wh[0][1] + hv.z * wh[0][2] + hv.w * wh[0][3];
        ah1[r] += hv.x * wh[1][0] + hv.y * wh[1][1] + hv.z * wh[1][2] + hv.w * wh[1][3];
        ah2[r] += hv.x * wh[2][0] + hv.y * wh[2][1] + hv.z * wh[2][2] + hv.w * wh[2][3];
      }
    }
  }

  // ---- gates, store, fused max-reduction ----
  float bi0 = bih[t], bi1 = bih[t + 256], bi2 = bih[t + 512];
  float bh0 = bhh[t], bh1 = bhh[t + 256], bh2 = bhh[t + 512];
  float gmax = -1e30f;
  #pragma unroll
  for (int r = 0; r < 16; ++r) {
    float sc = 1.f, hp = 0.f;
    float g0 = bh0, g1 = bh1, g2 = bh2;
    if constexpr (!FIRST) {
      sc = scales[r];
      g0 = sc * ah0[r] + bh0;
      g1 = sc * ah1[r] + bh1;
      g2 = sc * ah2[r] + bh2;
      hp = sc * hs[r][t];
    }
    float ir = ai0[r] + bi0, iz = ai1[r] + bi1, inn = ai2[r] + bi2;
    float rg = sigmoidf_(ir + g0);
    float z  = sigmoidf_(iz + g1);
    float n  = tanhf(inn + rg * g2);
    float hv = (1.f - z) * n + z * hp;
    int i = i0 + r;
    if (store_mode == 1) {
      Hout[(size_t)i * 256 + t] = hv;
    } else if (store_mode == 2 && ((i & 3) == 3)) {
      Hout[(size_t)(i >> 2) * 256 + t] = hv;
    }
    gmax = ((r & (bgrp - 1)) == 0) ? hv : fmaxf(gmax, hv);
    if ((r & (bgrp - 1)) == (bgrp - 1)) {
      int b = i >> bshift;
      atomicMax(outI + b * 256 + t, __float_as_int(gmax));
    }
  }
}

extern "C" void kernel_launch(void* const* d_in, const int* in_sizes, int n_in,
                              void* d_out, int out_size, void* d_ws, size_t ws_size,
                              hipStream_t stream) {
  const int*   tokens = (const int*)d_in[0];
  const float* emb    = (const float*)d_in[1];
  const float* wih    = (const float*)d_in[2];
  const float* whh    = (const float*)d_in[3];
  const float* bih    = (const float*)d_in[4];
  const float* bhh    = (const float*)d_in[5];
  const float* sw     = (const float*)d_in[6];
  const float* sb     = (const float*)d_in[7];
  const float* cw     = (const float*)d_in[8];
  float* ws = (float*)d_ws;

  float* wtih = ws;                       // 196608 floats
  float* wthh = ws + 196608;              // 196608
  float* u0p  = ws + 393216;              // 1 (padded to 64)
  float* Hs6  = ws + 393280;              // 8192*256
  float* Hs5  = Hs6 + 8192 * 256;         // 2048*256
  float* Hs4  = Hs5 + 2048 * 256;         // 512*256
  float* Hs3  = Hs4 + 512 * 256;          // 128*256
  float* Hs2  = Hs3 + 128 * 256;          // 32*256
  float* H1   = Hs2 + 32 * 256;           // 32*256  (full compact of level 1)

  int* outI = (int*)d_out;
  hipMemsetAsync(d_out, 0, 32 * 256 * sizeof(float), stream);
  prep_transpose<<<1536, 256, 0, stream>>>(wih, whh, wtih, wthh);
  u0_kernel<<<1, 64, 0, stream>>>(sb, cw, u0p);

  const float LN3  = 1.0986122886681098f;  // ln(A-1)
  const float LN31 = 3.4339872044851463f;  // ln(BS-1)

  // level 6 (FIRST: h=0, no attention). 32768 compact rows.
  level_kernel<true, false><<<2048, 256, 0, stream>>>(
      tokens + 43680, emb, wtih, wthh, bih, bhh, sw, sb, cw, u0p,
      nullptr, Hs6, outI, 0.f, 10, 16, 2);
  // level 5: 8192 rows
  level_kernel<false, false><<<512, 256, 0, stream>>>(
      tokens + 10912, emb, wtih, wthh, bih, bhh, sw, sb, cw, u0p,
      Hs6, Hs5, outI, LN3, 8, 16, 2);
  // level 4: 2048 rows
  level_kernel<false, false><<<128, 256, 0, stream>>>(
      tokens + 2720, emb, wtih, wthh, bih, bhh, sw, sb, cw, u0p,
      Hs5, Hs4, outI, LN3, 6, 16, 2);
  // level 3: 512 rows
  level_kernel<false, false><<<32, 256, 0, stream>>>(
      tokens + 672, emb, wtih, wthh, bih, bhh, sw, sb, cw, u0p,
      Hs4, Hs3, outI, LN3, 4, 16, 2);
  // level 2: 128 rows
  level_kernel<false, false><<<8, 256, 0, stream>>>(
      tokens + 160, emb, wtih, wthh, bih, bhh, sw, sb, cw, u0p,
      Hs3, Hs2, outI, LN3, 2, 4, 2);
  // level 1: 32 rows, store FULL compact for root
  level_kernel<false, false><<<2, 256, 0, stream>>>(
      tokens + 32, emb, wtih, wthh, bih, bhh, sw, sb, cw, u0p,
      Hs2, H1, outI, LN3, 0, 1, 1);
  // level 0 (ROOT): 32 rows, j=i, S=32
  level_kernel<false, true><<<2, 256, 0, stream>>>(
      tokens + 0, emb, wtih, wthh, bih, bhh, sw, sb, cw, u0p,
      H1, nullptr, outI, LN31, 0, 1, 0);
}

// Round 2
// 447.526 us; speedup vs baseline: 2.2054x; 2.2054x over previous
//
#include <hip/hip_runtime.h>
#include <hip/hip_bf16.h>
#include <math.h>

// BatchTreeEncoder: BS=32, A=4, D=6, H=E=256, V=50000
// Compact rows (j%4==3) only; per-row attention scale (diagonal identity);
// fused atomicMax epilogue. MFMA bf16 split-precision GEMMs:
//   gi  = (x_hi + x_lo) @ Wih_hi                 (2-term, B-rounding err ~3e-4)
//   gh  = (h_hi+h_lo)@Whh_hi + h_hi@Whh_lo       (3-term, err ~1e-7)
//   hsw = same 3-term with SW
// Weights pre-packed in per-lane MFMA B-frag layout: frag(kb,nf): lane l holds
// B[k = 32kb + 8*(l>>4) + j][n = 16nf + (l&15)], j=0..7 (16B contiguous).

typedef unsigned short u16;
typedef unsigned int u32;
typedef __attribute__((ext_vector_type(8))) short s8;   // bf16x8 operand (4 VGPR)
typedef __attribute__((ext_vector_type(4))) float f4;   // fp32x4 acc
#define MFMA16(a, b, c) __builtin_amdgcn_mfma_f32_16x16x32_bf16(a, b, c, 0, 0, 0)

__device__ __forceinline__ u16 f2bf(float f) {
  u32 x = __float_as_uint(f);
  return (u16)((x + 0x7fffu + ((x >> 16) & 1u)) >> 16);
}
__device__ __forceinline__ float bf2f(u16 u) { return __uint_as_float(((u32)u) << 16); }
__device__ __forceinline__ float sigmoidf_(float x) { return 1.0f / (1.0f + expf(-x)); }
__device__ __forceinline__ u32 packh(float h) {
  u16 hi = f2bf(h);
  u16 lo = f2bf(h - bf2f(hi));
  return (u32)hi | ((u32)lo << 16);
}

// ---- pack weights into MFMA B-frag layout (hi / lo planes) ----
// sections (groups of 8 elems): wihP_hi 24576 | whhP_hi 24576 | whhP_lo 24576 |
//                               swP_hi 8192 | swP_lo 8192   (total 90112 groups)
__global__ void prep_pack(const float* __restrict__ wih, const float* __restrict__ whh,
                          const float* __restrict__ sw,
                          u16* __restrict__ wihP, u16* __restrict__ whhPh,
                          u16* __restrict__ whhPl, u16* __restrict__ swPh,
                          u16* __restrict__ swPl) {
  int g = blockIdx.x * 256 + threadIdx.x;
  const float* src;
  u16* dst;
  int idx, NF, lomode, trans;
  if (g < 24576)      { idx = g;         src = wih; dst = wihP;  NF = 48; lomode = 0; trans = 1; }
  else if (g < 49152) { idx = g - 24576; src = whh; dst = whhPh; NF = 48; lomode = 0; trans = 1; }
  else if (g < 73728) { idx = g - 49152; src = whh; dst = whhPl; NF = 48; lomode = 1; trans = 1; }
  else if (g < 81920) { idx = g - 73728; src = sw;  dst = swPh;  NF = 16; lomode = 0; trans = 0; }
  else                { idx = g - 81920; src = sw;  dst = swPl;  NF = 16; lomode = 1; trans = 0; }
  int lane = idx & 63;
  int t2 = idx >> 6;
  int nf = t2 % NF, kb = t2 / NF;
  int n = nf * 16 + (lane & 15);
  int k0 = kb * 32 + (lane >> 4) * 8;
  float v[8];
  if (trans) {  // B[k][n] = W[n][k], W row-major [N][256]
    const float4* p = (const float4*)(src + (size_t)n * 256 + k0);
    float4 a = p[0], b = p[1];
    v[0] = a.x; v[1] = a.y; v[2] = a.z; v[3] = a.w;
    v[4] = b.x; v[5] = b.y; v[6] = b.z; v[7] = b.w;
  } else {      // B[k][n] = sw[k*256 + n]
    #pragma unroll
    for (int j = 0; j < 8; ++j) v[j] = src[(size_t)(k0 + j) * 256 + n];
  }
  u16 o[8];
  #pragma unroll
  for (int j = 0; j < 8; ++j) {
    u16 hi = f2bf(v[j]);
    o[j] = lomode ? f2bf(v[j] - bf2f(hi)) : hi;
  }
  u32* d = (u32*)(dst + (size_t)idx * 8);
  #pragma unroll
  for (int j = 0; j < 4; ++j) d[j] = (u32)o[2 * j] | ((u32)o[2 * j + 1] << 16);
}

__global__ void u0_kernel(const float* __restrict__ sb, const float* __restrict__ cw,
                          float* __restrict__ u0p) {
  int lane = threadIdx.x;
  float s = 0.f;
  #pragma unroll
  for (int q = 0; q < 4; ++q) { int k = lane + 64 * q; s += tanhf(sb[k]) * cw[k]; }
  #pragma unroll
  for (int off = 32; off >= 1; off >>= 1) s += __shfl_xor(s, off);
  if (lane == 0) u0p[0] = tanhf(s);
}

// 32 rows/block, 512 threads = 8 waves = (mf 0..1) x (cs 0..3).
// Wave (mf,cs): rows mf*16..+16, gate-cols [64cs,64cs+64) of each gate.
// A-plane LDS layout: elem (row,k) at plane[((k>>3)*32 + row)*8 + (k&7)]
template <bool FIRST, bool ROOT>
__global__ __launch_bounds__(512)
void level_kernel(const int* __restrict__ tokens, const float* __restrict__ emb,
                  const u16* __restrict__ wihP, const u16* __restrict__ whhPh,
                  const u16* __restrict__ whhPl, const u16* __restrict__ swPh,
                  const u16* __restrict__ swPl,
                  const float* __restrict__ bih, const float* __restrict__ bhh,
                  const float* __restrict__ sb, const float* __restrict__ cw,
                  const float* __restrict__ u0p,
                  const u32* __restrict__ Hnext, u32* __restrict__ Hout,
                  int* __restrict__ outI,
                  float logSm1, int bshift, int store_mode) {
  __shared__ u16 aX[2][8192];
  __shared__ u16 aH[2][FIRST ? 8 : 8192];
  __shared__ float pm[4][32];
  __shared__ float scl[32];

  const int t = threadIdx.x;
  const int i0 = blockIdx.x * 32;

  // ---- stage x (gather+split) and h_prev into LDS planes ----
  {
    int row = t & 31, seg = t >> 5;  // seg 0..15
    int i = i0 + row;
    int tok = tokens[ROOT ? i : 4 * i + 3];
    const float4* xr = (const float4*)(emb + (size_t)tok * 256);
    #pragma unroll
    for (int q = 0; q < 4; ++q) {
      float4 v = xr[seg * 4 + q];
      int k0 = seg * 16 + q * 4;
      int base = ((k0 >> 3) * 32 + row) * 8 + (k0 & 7);
      float vv[4] = {v.x, v.y, v.z, v.w};
      u16 hh[4], ll[4];
      #pragma unroll
      for (int e = 0; e < 4; ++e) { hh[e] = f2bf(vv[e]); ll[e] = f2bf(vv[e] - bf2f(hh[e])); }
      *(uint2*)&aX[0][base] = {(u32)hh[0] | ((u32)hh[1] << 16), (u32)hh[2] | ((u32)hh[3] << 16)};
      *(uint2*)&aX[1][base] = {(u32)ll[0] | ((u32)ll[1] << 16), (u32)ll[2] | ((u32)ll[3] << 16)};
    }
    if constexpr (!FIRST) {
      const uint4* hr = (const uint4*)(Hnext + (size_t)i * 256);
      #pragma unroll
      for (int q = 0; q < 4; ++q) {
        uint4 u = hr[seg * 4 + q];
        int k0 = seg * 16 + q * 4;
        int base = ((k0 >> 3) * 32 + row) * 8 + (k0 & 7);
        u32 uu[4] = {u.x, u.y, u.z, u.w};
        *(uint2*)&aH[0][base] = {(uu[0] & 0xffffu) | ((uu[1] & 0xffffu) << 16),
                                 (uu[2] & 0xffffu) | ((uu[3] & 0xffffu) << 16)};
        *(uint2*)&aH[1][base] = {(uu[0] >> 16) | (uu[1] & 0xffff0000u),
                                 (uu[2] >> 16) | (uu[3] & 0xffff0000u)};
      }
    }
  }
  __syncthreads();

  const int lane = t & 63, wid = t >> 6;
  const int mf = wid >> 2, cs = wid & 3;
  const int asub = lane >> 4;
  const int arow = mf * 16 + (lane & 15);

  f4 gi[3][4], gh[3][4], sa[4];
  #pragma unroll
  for (int g = 0; g < 3; ++g)
    #pragma unroll
    for (int f = 0; f < 4; ++f) { gi[g][f] = (f4){0.f, 0.f, 0.f, 0.f}; gh[g][f] = (f4){0.f, 0.f, 0.f, 0.f}; }
  #pragma unroll
  for (int f = 0; f < 4; ++f) sa[f] = (f4){0.f, 0.f, 0.f, 0.f};

  #pragma unroll
  for (int kb = 0; kb < 8; ++kb) {
    int abase = ((kb * 4 + asub) * 32 + arow) * 8;
    s8 axh = *(const s8*)&aX[0][abase];
    s8 axl = *(const s8*)&aX[1][abase];
    s8 ahh, ahl;
    if constexpr (!FIRST) { ahh = *(const s8*)&aH[0][abase]; ahl = *(const s8*)&aH[1][abase]; }
    #pragma unroll
    for (int g = 0; g < 3; ++g) {
      #pragma unroll
      for (int f = 0; f < 4; ++f) {
        int nf = 16 * g + 4 * cs + f;
        size_t bo = ((size_t)(kb * 48 + nf) * 64 + lane) * 8;
        s8 b = *(const s8*)&wihP[bo];
        gi[g][f] = MFMA16(axh, b, gi[g][f]);
        gi[g][f] = MFMA16(axl, b, gi[g][f]);
        if constexpr (!FIRST) {
          s8 bh = *(const s8*)&whhPh[bo];
          s8 bl = *(const s8*)&whhPl[bo];
          gh[g][f] = MFMA16(ahh, bh, gh[g][f]);
          gh[g][f] = MFMA16(ahl, bh, gh[g][f]);
          gh[g][f] = MFMA16(ahh, bl, gh[g][f]);
        }
      }
    }
    if constexpr (!FIRST) {
      #pragma unroll
      for (int f = 0; f < 4; ++f) {
        int nfs = 4 * cs + f;
        size_t so = ((size_t)(kb * 16 + nfs) * 64 + lane) * 8;
        s8 bh = *(const s8*)&swPh[so];
        s8 bl = *(const s8*)&swPl[so];
        sa[f] = MFMA16(ahh, bh, sa[f]);
        sa[f] = MFMA16(ahl, bh, sa[f]);
        sa[f] = MFMA16(ahh, bl, sa[f]);
      }
    }
  }

  // ---- attention scale: u = tanh(sum_k tanh(hsw+sb)*cw); sc = sigmoid(u-u0-lnSm1)
  if constexpr (!FIRST) {
    float part[4] = {0.f, 0.f, 0.f, 0.f};
    #pragma unroll
    for (int f = 0; f < 4; ++f) {
      int k = cs * 64 + f * 16 + (lane & 15);
      float sbk = sb[k], cwk = cw[k];
      #pragma unroll
      for (int j = 0; j < 4; ++j) part[j] += tanhf(sa[f][j] + sbk) * cwk;
    }
    #pragma unroll
    for (int j = 0; j < 4; ++j) {
      part[j] += __shfl_xor(part[j], 1);
      part[j] += __shfl_xor(part[j], 2);
      part[j] += __shfl_xor(part[j], 4);
      part[j] += __shfl_xor(part[j], 8);
    }
    if ((lane & 15) == 0) {
      #pragma unroll
      for (int j = 0; j < 4; ++j) pm[cs][mf * 16 + asub * 4 + j] = part[j];
    }
    __syncthreads();
    if (t < 32) {
      float v = pm[0][t] + pm[1][t] + pm[2][t] + pm[3][t];
      scl[t] = sigmoidf_(tanhf(v) - u0p[0] - logSm1);
    }
    __syncthreads();
  }

  // ---- gates + store + fused max ----
  const int colb = cs * 64 + (lane & 15);
  const int r0 = mf * 16 + asub * 4;
  #pragma unroll
  for (int f = 0; f < 4; ++f) {
    int col = colb + 16 * f;
    float bi0 = bih[col], bi1 = bih[256 + col], bi2 = bih[512 + col];
    float bh0 = bhh[col], bh1 = bhh[256 + col], bh2 = bhh[512 + col];
    float hmax = -1e30f;
    #pragma unroll
    for (int j = 0; j < 4; ++j) {
      int row = r0 + j;
      int i = i0 + row;
      float ir = gi[0][f][j] + bi0, iz = gi[1][f][j] + bi1, inn = gi[2][f][j] + bi2;
      float g0 = bh0, g1 = bh1, g2 = bh2, hp = 0.f;
      if constexpr (!FIRST) {
        float sc = scl[row];
        g0 += sc * gh[0][f][j];
        g1 += sc * gh[1][f][j];
        g2 += sc * gh[2][f][j];
        int hidx = ((col >> 3) * 32 + row) * 8 + (col & 7);
        hp = sc * (bf2f(aH[0][hidx]) + bf2f(aH[1][hidx]));
      }
      float r = sigmoidf_(ir + g0);
      float z = sigmoidf_(iz + g1);
      float n = tanhf(inn + r * g2);
      float h = (1.f - z) * n + z * hp;
      if (store_mode == 1) {
        Hout[(size_t)i * 256 + col] = packh(h);
      } else if (store_mode == 2 && ((i & 3) == 3)) {
        Hout[(size_t)(i >> 2) * 256 + col] = packh(h);
      }
      if (bshift >= 2) {
        hmax = (j == 0) ? h : fmaxf(hmax, h);
      } else {
        atomicMax(outI + (size_t)i * 256 + col, __float_as_int(h));
      }
    }
    if (bshift >= 2) {
      int b = (i0 + r0) >> bshift;
      atomicMax(outI + (size_t)b * 256 + col, __float_as_int(hmax));
    }
  }
}

extern "C" void kernel_launch(void* const* d_in, const int* in_sizes, int n_in,
                              void* d_out, int out_size, void* d_ws, size_t ws_size,
                              hipStream_t stream) {
  const int*   tokens = (const int*)d_in[0];
  const float* emb    = (const float*)d_in[1];
  const float* wih    = (const float*)d_in[2];
  const float* whh    = (const float*)d_in[3];
  const float* bih    = (const float*)d_in[4];
  const float* bhh    = (const float*)d_in[5];
  const float* sw     = (const float*)d_in[6];
  const float* sb     = (const float*)d_in[7];
  const float* cw     = (const float*)d_in[8];

  char* ws = (char*)d_ws;
  u16* wihP  = (u16*)ws;                       // 196608 u16
  u16* whhPh = wihP + 196608;
  u16* whhPl = whhPh + 196608;
  u16* swPh  = whhPl + 196608;                 // 65536
  u16* swPl  = swPh + 65536;
  float* u0p = (float*)(ws + 1441792);         // 64 floats
  u32* Hs6 = (u32*)(ws + 1442048);             // 8192*256
  u32* Hs5 = Hs6 + 8192 * 256;                 // 2048*256
  u32* Hs4 = Hs5 + 2048 * 256;                 // 512*256
  u32* Hs3 = Hs4 + 512 * 256;                  // 128*256
  u32* Hs2 = Hs3 + 128 * 256;                  // 32*256
  u32* H1  = Hs2 + 32 * 256;                   // 32*256

  int* outI = (int*)d_out;
  hipMemsetAsync(d_out, 0, 32 * 256 * sizeof(float), stream);
  prep_pack<<<352, 256, 0, stream>>>(wih, whh, sw, wihP, whhPh, whhPl, swPh, swPl);
  u0_kernel<<<1, 64, 0, stream>>>(sb, cw, u0p);

  const float LN3  = 1.0986122886681098f;   // ln(A-1)
  const float LN31 = 3.4339872044851463f;   // ln(BS-1)

  level_kernel<true, false><<<1024, 512, 0, stream>>>(
      tokens + 43680, emb, wihP, whhPh, whhPl, swPh, swPl, bih, bhh, sb, cw, u0p,
      nullptr, Hs6, outI, 0.f, 10, 2);
  level_kernel<false, false><<<256, 512, 0, stream>>>(
      tokens + 10912, emb, wihP, whhPh, whhPl, swPh, swPl, bih, bhh, sb, cw, u0p,
      Hs6, Hs5, outI, LN3, 8, 2);
  level_kernel<false, false><<<64, 512, 0, stream>>>(
      tokens + 2720, emb, wihP, whhPh, whhPl, swPh, swPl, bih, bhh, sb, cw, u0p,
      Hs5, Hs4, outI, LN3, 6, 2);
  level_kernel<false, false><<<16, 512, 0, stream>>>(
      tokens + 672, emb, wihP, whhPh, whhPl, swPh, swPl, bih, bhh, sb, cw, u0p,
      Hs4, Hs3, outI, LN3, 4, 2);
  level_kernel<false, false><<<4, 512, 0, stream>>>(
      tokens + 160, emb, wihP, whhPh, whhPl, swPh, swPl, bih, bhh, sb, cw, u0p,
      Hs3, Hs2, outI, LN3, 2, 2);
  level_kernel<false, false><<<1, 512, 0, stream>>>(
      tokens + 32, emb, wihP, whhPh, whhPl, swPh, swPl, bih, bhh, sb, cw, u0p,
      Hs2, H1, outI, LN3, 0, 1);
  level_kernel<false, true><<<1, 512, 0, stream>>>(
      tokens + 0, emb, wihP, whhPh, whhPl, swPh, swPl, bih, bhh, sb, cw, u0p,
      H1, nullptr, outI, LN31, 0, 0);
}

// Round 3
// 320.277 us; speedup vs baseline: 3.0817x; 1.3973x over previous
//
#include <hip/hip_runtime.h>
#include <hip/hip_bf16.h>
#include <math.h>

// BatchTreeEncoder: BS=32, A=4, D=6, H=E=256, V=50000
// Compact rows (j%4==3) only; per-row attention scale (diagonal identity);
// fused atomicMax epilogue. MFMA bf16 split-precision GEMMs:
//   gi  = (x_hi + x_lo) @ Wih_hi                 (2-term)
//   gh  = (h_hi+h_lo)@Whh_hi + h_hi@Whh_lo       (3-term)
//   hsw = (h_hi+h_lo)@SW_hi                      (2-term, B hi only)
// Wave mapping (round 3): wave w owns col-frags {2w, 2w+1} (16 cols each, same
// frag index in all 3 gates) for BOTH 16-row M-frags -> each B frag loaded
// once per block, 68 MFMA : 20 B-loads per K-step per wave.

typedef unsigned short u16;
typedef unsigned int u32;
typedef __attribute__((ext_vector_type(8))) short s8;   // bf16x8 operand (4 VGPR)
typedef __attribute__((ext_vector_type(4))) float f4;   // fp32x4 acc
#define MFMA16(a, b, c) __builtin_amdgcn_mfma_f32_16x16x32_bf16(a, b, c, 0, 0, 0)

__device__ __forceinline__ u16 f2bf(float f) {
  u32 x = __float_as_uint(f);
  return (u16)((x + 0x7fffu + ((x >> 16) & 1u)) >> 16);
}
__device__ __forceinline__ float bf2f(u16 u) { return __uint_as_float(((u32)u) << 16); }
__device__ __forceinline__ float sigmoidf_(float x) { return 1.0f / (1.0f + expf(-x)); }
__device__ __forceinline__ u32 packh(float h) {
  u16 hi = f2bf(h);
  u16 lo = f2bf(h - bf2f(hi));
  return (u32)hi | ((u32)lo << 16);
}

// ---- pack weights into MFMA B-frag layout (hi / lo planes) ----
__global__ void prep_pack(const float* __restrict__ wih, const float* __restrict__ whh,
                          const float* __restrict__ sw,
                          u16* __restrict__ wihP, u16* __restrict__ whhPh,
                          u16* __restrict__ whhPl, u16* __restrict__ swPh,
                          u16* __restrict__ swPl) {
  int g = blockIdx.x * 256 + threadIdx.x;
  const float* src;
  u16* dst;
  int idx, NF, lomode, trans;
  if (g < 24576)      { idx = g;         src = wih; dst = wihP;  NF = 48; lomode = 0; trans = 1; }
  else if (g < 49152) { idx = g - 24576; src = whh; dst = whhPh; NF = 48; lomode = 0; trans = 1; }
  else if (g < 73728) { idx = g - 49152; src = whh; dst = whhPl; NF = 48; lomode = 1; trans = 1; }
  else if (g < 81920) { idx = g - 73728; src = sw;  dst = swPh;  NF = 16; lomode = 0; trans = 0; }
  else                { idx = g - 81920; src = sw;  dst = swPl;  NF = 16; lomode = 1; trans = 0; }
  int lane = idx & 63;
  int t2 = idx >> 6;
  int nf = t2 % NF, kb = t2 / NF;
  int n = nf * 16 + (lane & 15);
  int k0 = kb * 32 + (lane >> 4) * 8;
  float v[8];
  if (trans) {
    const float4* p = (const float4*)(src + (size_t)n * 256 + k0);
    float4 a = p[0], b = p[1];
    v[0] = a.x; v[1] = a.y; v[2] = a.z; v[3] = a.w;
    v[4] = b.x; v[5] = b.y; v[6] = b.z; v[7] = b.w;
  } else {
    #pragma unroll
    for (int j = 0; j < 8; ++j) v[j] = src[(size_t)(k0 + j) * 256 + n];
  }
  u16 o[8];
  #pragma unroll
  for (int j = 0; j < 8; ++j) {
    u16 hi = f2bf(v[j]);
    o[j] = lomode ? f2bf(v[j] - bf2f(hi)) : hi;
  }
  u32* d = (u32*)(dst + (size_t)idx * 8);
  #pragma unroll
  for (int j = 0; j < 4; ++j) d[j] = (u32)o[2 * j] | ((u32)o[2 * j + 1] << 16);
}

__global__ void u0_kernel(const float* __restrict__ sb, const float* __restrict__ cw,
                          float* __restrict__ u0p) {
  int lane = threadIdx.x;
  float s = 0.f;
  #pragma unroll
  for (int q = 0; q < 4; ++q) { int k = lane + 64 * q; s += tanhf(sb[k]) * cw[k]; }
  #pragma unroll
  for (int off = 32; off >= 1; off >>= 1) s += __shfl_xor(s, off);
  if (lane == 0) u0p[0] = tanhf(s);
}

// 32 rows/block, 512 threads = 8 waves. Wave w: col-frags {2w,2w+1}, both mf.
// A-plane LDS layout: elem (row,k) at plane[((k>>3)*32 + row)*8 + (k&7)]
template <bool FIRST, bool ROOT>
__global__ __launch_bounds__(512, (FIRST ? 4 : 2))
void level_kernel(const int* __restrict__ tokens, const float* __restrict__ emb,
                  const u16* __restrict__ wihP, const u16* __restrict__ whhPh,
                  const u16* __restrict__ whhPl, const u16* __restrict__ swPh,
                  const float* __restrict__ bih, const float* __restrict__ bhh,
                  const float* __restrict__ sb, const float* __restrict__ cw,
                  const float* __restrict__ u0p,
                  const u32* __restrict__ Hnext, u32* __restrict__ Hout,
                  int* __restrict__ outI,
                  float logSm1, int bshift, int store_mode) {
  __shared__ u16 aX[2][8192];
  __shared__ u16 aH[2][FIRST ? 8 : 8192];
  __shared__ float pm[8][32];
  __shared__ float scl[32];

  const int t = threadIdx.x;
  const int i0 = blockIdx.x * 32;

  // ---- stage x (gather+split) and h_prev into LDS planes ----
  {
    int row = t & 31, seg = t >> 5;  // seg 0..15
    int i = i0 + row;
    int tok = tokens[ROOT ? i : 4 * i + 3];
    const float4* xr = (const float4*)(emb + (size_t)tok * 256);
    #pragma unroll
    for (int q = 0; q < 4; ++q) {
      float4 v = xr[seg * 4 + q];
      int k0 = seg * 16 + q * 4;
      int base = ((k0 >> 3) * 32 + row) * 8 + (k0 & 7);
      float vv[4] = {v.x, v.y, v.z, v.w};
      u16 hh[4], ll[4];
      #pragma unroll
      for (int e = 0; e < 4; ++e) { hh[e] = f2bf(vv[e]); ll[e] = f2bf(vv[e] - bf2f(hh[e])); }
      *(uint2*)&aX[0][base] = {(u32)hh[0] | ((u32)hh[1] << 16), (u32)hh[2] | ((u32)hh[3] << 16)};
      *(uint2*)&aX[1][base] = {(u32)ll[0] | ((u32)ll[1] << 16), (u32)ll[2] | ((u32)ll[3] << 16)};
    }
    if constexpr (!FIRST) {
      const uint4* hr = (const uint4*)(Hnext + (size_t)i * 256);
      #pragma unroll
      for (int q = 0; q < 4; ++q) {
        uint4 u = hr[seg * 4 + q];
        int k0 = seg * 16 + q * 4;
        int base = ((k0 >> 3) * 32 + row) * 8 + (k0 & 7);
        u32 uu[4] = {u.x, u.y, u.z, u.w};
        *(uint2*)&aH[0][base] = {(uu[0] & 0xffffu) | ((uu[1] & 0xffffu) << 16),
                                 (uu[2] & 0xffffu) | ((uu[3] & 0xffffu) << 16)};
        *(uint2*)&aH[1][base] = {(uu[0] >> 16) | (uu[1] & 0xffff0000u),
                                 (uu[2] >> 16) | (uu[3] & 0xffff0000u)};
      }
    }
  }
  __syncthreads();

  const int lane = t & 63, w = t >> 6;
  const int asub = lane >> 4;
  const int l15 = lane & 15;

  f4 gi[3][2][2], gh[3][2][2], sa[2][2];
  #pragma unroll
  for (int g = 0; g < 3; ++g)
    #pragma unroll
    for (int jc = 0; jc < 2; ++jc)
      #pragma unroll
      for (int mf = 0; mf < 2; ++mf) {
        gi[g][jc][mf] = (f4){0.f, 0.f, 0.f, 0.f};
        if constexpr (!FIRST) gh[g][jc][mf] = (f4){0.f, 0.f, 0.f, 0.f};
      }
  if constexpr (!FIRST) {
    #pragma unroll
    for (int jc = 0; jc < 2; ++jc)
      #pragma unroll
      for (int mf = 0; mf < 2; ++mf) sa[jc][mf] = (f4){0.f, 0.f, 0.f, 0.f};
  }

  #pragma unroll
  for (int kb = 0; kb < 8; ++kb) {
    s8 axh[2], axl[2], ahh[2], ahl[2];
    #pragma unroll
    for (int mf = 0; mf < 2; ++mf) {
      int abase = ((kb * 4 + asub) * 32 + 16 * mf + l15) * 8;
      axh[mf] = *(const s8*)&aX[0][abase];
      axl[mf] = *(const s8*)&aX[1][abase];
      if constexpr (!FIRST) {
        ahh[mf] = *(const s8*)&aH[0][abase];
        ahl[mf] = *(const s8*)&aH[1][abase];
      }
    }
    #pragma unroll
    for (int jc = 0; jc < 2; ++jc) {
      const int cf = 2 * w + jc;
      #pragma unroll
      for (int g = 0; g < 3; ++g) {
        size_t bo = ((size_t)(kb * 48 + 16 * g + cf) * 64 + lane) * 8;
        s8 b = *(const s8*)&wihP[bo];
        gi[g][jc][0] = MFMA16(axh[0], b, gi[g][jc][0]);
        gi[g][jc][1] = MFMA16(axh[1], b, gi[g][jc][1]);
        gi[g][jc][0] = MFMA16(axl[0], b, gi[g][jc][0]);
        gi[g][jc][1] = MFMA16(axl[1], b, gi[g][jc][1]);
        if constexpr (!FIRST) {
          s8 bh = *(const s8*)&whhPh[bo];
          s8 bl = *(const s8*)&whhPl[bo];
          gh[g][jc][0] = MFMA16(ahh[0], bh, gh[g][jc][0]);
          gh[g][jc][1] = MFMA16(ahh[1], bh, gh[g][jc][1]);
          gh[g][jc][0] = MFMA16(ahl[0], bh, gh[g][jc][0]);
          gh[g][jc][1] = MFMA16(ahl[1], bh, gh[g][jc][1]);
          gh[g][jc][0] = MFMA16(ahh[0], bl, gh[g][jc][0]);
          gh[g][jc][1] = MFMA16(ahh[1], bl, gh[g][jc][1]);
        }
      }
      if constexpr (!FIRST) {
        size_t so = ((size_t)(kb * 16 + cf) * 64 + lane) * 8;
        s8 bsw = *(const s8*)&swPh[so];
        sa[jc][0] = MFMA16(ahh[0], bsw, sa[jc][0]);
        sa[jc][1] = MFMA16(ahh[1], bsw, sa[jc][1]);
        sa[jc][0] = MFMA16(ahl[0], bsw, sa[jc][0]);
        sa[jc][1] = MFMA16(ahl[1], bsw, sa[jc][1]);
      }
    }
  }

  // ---- attention scale: u = tanh(sum_k tanh(hsw+sb)*cw); sc = sigmoid(u-u0-lnSm1)
  if constexpr (!FIRST) {
    float part[2][4] = {{0.f, 0.f, 0.f, 0.f}, {0.f, 0.f, 0.f, 0.f}};
    #pragma unroll
    for (int jc = 0; jc < 2; ++jc) {
      int k = 16 * (2 * w + jc) + l15;
      float sbk = sb[k], cwk = cw[k];
      #pragma unroll
      for (int mf = 0; mf < 2; ++mf)
        #pragma unroll
        for (int j = 0; j < 4; ++j) part[mf][j] += tanhf(sa[jc][mf][j] + sbk) * cwk;
    }
    #pragma unroll
    for (int mf = 0; mf < 2; ++mf)
      #pragma unroll
      for (int j = 0; j < 4; ++j) {
        part[mf][j] += __shfl_xor(part[mf][j], 1);
        part[mf][j] += __shfl_xor(part[mf][j], 2);
        part[mf][j] += __shfl_xor(part[mf][j], 4);
        part[mf][j] += __shfl_xor(part[mf][j], 8);
      }
    if (l15 == 0) {
      #pragma unroll
      for (int mf = 0; mf < 2; ++mf)
        #pragma unroll
        for (int j = 0; j < 4; ++j) pm[w][16 * mf + 4 * asub + j] = part[mf][j];
    }
    __syncthreads();
    if (t < 32) {
      float v = 0.f;
      #pragma unroll
      for (int q = 0; q < 8; ++q) v += pm[q][t];
      scl[t] = sigmoidf_(tanhf(v) - u0p[0] - logSm1);
    }
    __syncthreads();
  }

  // ---- gates + store + fused max ----
  #pragma unroll
  for (int jc = 0; jc < 2; ++jc) {
    const int col = 16 * (2 * w + jc) + l15;
    const float bi0 = bih[col], bi1 = bih[256 + col], bi2 = bih[512 + col];
    const float bh0 = bhh[col], bh1 = bhh[256 + col], bh2 = bhh[512 + col];
    #pragma unroll
    for (int mf = 0; mf < 2; ++mf) {
      const int r0 = 16 * mf + 4 * asub;
      float hmax = -1e30f;
      #pragma unroll
      for (int j = 0; j < 4; ++j) {
        const int row = r0 + j;
        const int i = i0 + row;
        float ir = gi[0][jc][mf][j] + bi0;
        float iz = gi[1][jc][mf][j] + bi1;
        float inn = gi[2][jc][mf][j] + bi2;
        float g0 = bh0, g1 = bh1, g2 = bh2, hp = 0.f;
        if constexpr (!FIRST) {
          float sc = scl[row];
          g0 += sc * gh[0][jc][mf][j];
          g1 += sc * gh[1][jc][mf][j];
          g2 += sc * gh[2][jc][mf][j];
          int hidx = ((col >> 3) * 32 + row) * 8 + (col & 7);
          hp = sc * (bf2f(aH[0][hidx]) + bf2f(aH[1][hidx]));
        }
        float r = sigmoidf_(ir + g0);
        float z = sigmoidf_(iz + g1);
        float n = tanhf(inn + r * g2);
        float h = (1.f - z) * n + z * hp;
        if (store_mode == 1) {
          Hout[(size_t)i * 256 + col] = packh(h);
        } else if (store_mode == 2 && ((i & 3) == 3)) {
          Hout[(size_t)(i >> 2) * 256 + col] = packh(h);
        }
        if (bshift >= 2) {
          hmax = (j == 0) ? h : fmaxf(hmax, h);
        } else {
          atomicMax(outI + (size_t)i * 256 + col, __float_as_int(h));
        }
      }
      if (bshift >= 2) {
        atomicMax(outI + (size_t)((i0 + r0) >> bshift) * 256 + col, __float_as_int(hmax));
      }
    }
  }
}

extern "C" void kernel_launch(void* const* d_in, const int* in_sizes, int n_in,
                              void* d_out, int out_size, void* d_ws, size_t ws_size,
                              hipStream_t stream) {
  const int*   tokens = (const int*)d_in[0];
  const float* emb    = (const float*)d_in[1];
  const float* wih    = (const float*)d_in[2];
  const float* whh    = (const float*)d_in[3];
  const float* bih    = (const float*)d_in[4];
  const float* bhh    = (const float*)d_in[5];
  const float* sw     = (const float*)d_in[6];
  const float* sb     = (const float*)d_in[7];
  const float* cw     = (const float*)d_in[8];

  char* ws = (char*)d_ws;
  u16* wihP  = (u16*)ws;                       // 196608 u16
  u16* whhPh = wihP + 196608;
  u16* whhPl = whhPh + 196608;
  u16* swPh  = whhPl + 196608;                 // 65536
  u16* swPl  = swPh + 65536;                   // (packed, unused by level_kernel)
  float* u0p = (float*)(ws + 1441792);         // 64 floats
  u32* Hs6 = (u32*)(ws + 1442048);             // 8192*256
  u32* Hs5 = Hs6 + 8192 * 256;                 // 2048*256
  u32* Hs4 = Hs5 + 2048 * 256;                 // 512*256
  u32* Hs3 = Hs4 + 512 * 256;                  // 128*256
  u32* Hs2 = Hs3 + 128 * 256;                  // 32*256
  u32* H1  = Hs2 + 32 * 256;                   // 32*256

  int* outI = (int*)d_out;
  hipMemsetAsync(d_out, 0, 32 * 256 * sizeof(float), stream);
  prep_pack<<<352, 256, 0, stream>>>(wih, whh, sw, wihP, whhPh, whhPl, swPh, swPl);
  u0_kernel<<<1, 64, 0, stream>>>(sb, cw, u0p);

  const float LN3  = 1.0986122886681098f;   // ln(A-1)
  const float LN31 = 3.4339872044851463f;   // ln(BS-1)

  level_kernel<true, false><<<1024, 512, 0, stream>>>(
      tokens + 43680, emb, wihP, whhPh, whhPl, swPh, bih, bhh, sb, cw, u0p,
      nullptr, Hs6, outI, 0.f, 10, 2);
  level_kernel<false, false><<<256, 512, 0, stream>>>(
      tokens + 10912, emb, wihP, whhPh, whhPl, swPh, bih, bhh, sb, cw, u0p,
      Hs6, Hs5, outI, LN3, 8, 2);
  level_kernel<false, false><<<64, 512, 0, stream>>>(
      tokens + 2720, emb, wihP, whhPh, whhPl, swPh, bih, bhh, sb, cw, u0p,
      Hs5, Hs4, outI, LN3, 6, 2);
  level_kernel<false, false><<<16, 512, 0, stream>>>(
      tokens + 672, emb, wihP, whhPh, whhPl, swPh, bih, bhh, sb, cw, u0p,
      Hs4, Hs3, outI, LN3, 4, 2);
  level_kernel<false, false><<<4, 512, 0, stream>>>(
      tokens + 160, emb, wihP, whhPh, whhPl, swPh, bih, bhh, sb, cw, u0p,
      Hs3, Hs2, outI, LN3, 2, 2);
  level_kernel<false, false><<<1, 512, 0, stream>>>(
      tokens + 32, emb, wihP, whhPh, whhPl, swPh, bih, bhh, sb, cw, u0p,
      Hs2, H1, outI, LN3, 0, 1);
  level_kernel<false, true><<<1, 512, 0, stream>>>(
      tokens + 0, emb, wihP, whhPh, whhPl, swPh, bih, bhh, sb, cw, u0p,
      H1, nullptr, outI, LN31, 0, 0);
}

// Round 4
// 256.869 us; speedup vs baseline: 3.8424x; 1.2468x over previous
//
#include <hip/hip_runtime.h>
#include <hip/hip_bf16.h>
#include <math.h>

// BatchTreeEncoder: BS=32, A=4, D=6, H=E=256, V=50000
// Compact rows (j%4==3) only; per-row attention scale (diagonal identity);
// fused atomicMax epilogue. MFMA bf16 split-precision GEMMs:
//   gi  = (x_hi + x_lo) @ Wih_hi
//   gh  = (h_hi+h_lo)@Whh_hi + h_hi@Whh_lo
//   hsw = (h_hi+h_lo)@SW_hi
// Big levels (6,5,4): level_kernel, 32 rows/block, wave w owns col-frags
// {2w,2w+1} for both m-frags. Tail levels (3,2,1,0): tail_kernel, grid
// nrb x 4 col-split (64 cols/block) + register-double-buffered B fragments
// (latency fix for the 1-block 103us dispatches seen in round 3).

typedef unsigned short u16;
typedef unsigned int u32;
typedef __attribute__((ext_vector_type(8))) short s8;   // bf16x8 operand (4 VGPR)
typedef __attribute__((ext_vector_type(4))) float f4;   // fp32x4 acc
#define MFMA16(a, b, c) __builtin_amdgcn_mfma_f32_16x16x32_bf16(a, b, c, 0, 0, 0)

__device__ __forceinline__ u16 f2bf(float f) {
  u32 x = __float_as_uint(f);
  return (u16)((x + 0x7fffu + ((x >> 16) & 1u)) >> 16);
}
__device__ __forceinline__ float bf2f(u16 u) { return __uint_as_float(((u32)u) << 16); }
__device__ __forceinline__ float sigmoidf_(float x) { return 1.0f / (1.0f + expf(-x)); }
__device__ __forceinline__ u32 packh(float h) {
  u16 hi = f2bf(h);
  u16 lo = f2bf(h - bf2f(hi));
  return (u32)hi | ((u32)lo << 16);
}

// ---- pack weights into MFMA B-frag layout (hi / lo planes) ----
__global__ void prep_pack(const float* __restrict__ wih, const float* __restrict__ whh,
                          const float* __restrict__ sw,
                          u16* __restrict__ wihP, u16* __restrict__ whhPh,
                          u16* __restrict__ whhPl, u16* __restrict__ swPh) {
  int g = blockIdx.x * 256 + threadIdx.x;   // 0..81919
  const float* src;
  u16* dst;
  int idx, NF, lomode, trans;
  if (g < 24576)      { idx = g;         src = wih; dst = wihP;  NF = 48; lomode = 0; trans = 1; }
  else if (g < 49152) { idx = g - 24576; src = whh; dst = whhPh; NF = 48; lomode = 0; trans = 1; }
  else if (g < 73728) { idx = g - 49152; src = whh; dst = whhPl; NF = 48; lomode = 1; trans = 1; }
  else                { idx = g - 73728; src = sw;  dst = swPh;  NF = 16; lomode = 0; trans = 0; }
  int lane = idx & 63;
  int t2 = idx >> 6;
  int nf = t2 % NF, kb = t2 / NF;
  int n = nf * 16 + (lane & 15);
  int k0 = kb * 32 + (lane >> 4) * 8;
  float v[8];
  if (trans) {
    const float4* p = (const float4*)(src + (size_t)n * 256 + k0);
    float4 a = p[0], b = p[1];
    v[0] = a.x; v[1] = a.y; v[2] = a.z; v[3] = a.w;
    v[4] = b.x; v[5] = b.y; v[6] = b.z; v[7] = b.w;
  } else {
    #pragma unroll
    for (int j = 0; j < 8; ++j) v[j] = src[(size_t)(k0 + j) * 256 + n];
  }
  u16 o[8];
  #pragma unroll
  for (int j = 0; j < 8; ++j) {
    u16 hi = f2bf(v[j]);
    o[j] = lomode ? f2bf(v[j] - bf2f(hi)) : hi;
  }
  u32* d = (u32*)(dst + (size_t)idx * 8);
  #pragma unroll
  for (int j = 0; j < 4; ++j) d[j] = (u32)o[2 * j] | ((u32)o[2 * j + 1] << 16);
}

__global__ void u0_kernel(const float* __restrict__ sb, const float* __restrict__ cw,
                          float* __restrict__ u0p) {
  int lane = threadIdx.x;
  float s = 0.f;
  #pragma unroll
  for (int q = 0; q < 4; ++q) { int k = lane + 64 * q; s += tanhf(sb[k]) * cw[k]; }
  #pragma unroll
  for (int off = 32; off >= 1; off >>= 1) s += __shfl_xor(s, off);
  if (lane == 0) u0p[0] = tanhf(s);
}

// ---- big-level kernel (levels 6,5,4) ----
template <bool FIRST, bool ROOT>
__global__ __launch_bounds__(512, (FIRST ? 4 : 2))
void level_kernel(const int* __restrict__ tokens, const float* __restrict__ emb,
                  const u16* __restrict__ wihP, const u16* __restrict__ whhPh,
                  const u16* __restrict__ whhPl, const u16* __restrict__ swPh,
                  const float* __restrict__ bih, const float* __restrict__ bhh,
                  const float* __restrict__ sb, const float* __restrict__ cw,
                  const float* __restrict__ u0p,
                  const u32* __restrict__ Hnext, u32* __restrict__ Hout,
                  int* __restrict__ outI,
                  float logSm1, int bshift, int store_mode) {
  __shared__ u16 aX[2][8192];
  __shared__ u16 aH[2][FIRST ? 8 : 8192];
  __shared__ float pm[8][32];
  __shared__ float scl[32];

  const int t = threadIdx.x;
  const int i0 = blockIdx.x * 32;

  {
    int row = t & 31, seg = t >> 5;
    int i = i0 + row;
    int tok = tokens[ROOT ? i : 4 * i + 3];
    const float4* xr = (const float4*)(emb + (size_t)tok * 256);
    #pragma unroll
    for (int q = 0; q < 4; ++q) {
      float4 v = xr[seg * 4 + q];
      int k0 = seg * 16 + q * 4;
      int base = ((k0 >> 3) * 32 + row) * 8 + (k0 & 7);
      float vv[4] = {v.x, v.y, v.z, v.w};
      u16 hh[4], ll[4];
      #pragma unroll
      for (int e = 0; e < 4; ++e) { hh[e] = f2bf(vv[e]); ll[e] = f2bf(vv[e] - bf2f(hh[e])); }
      *(uint2*)&aX[0][base] = {(u32)hh[0] | ((u32)hh[1] << 16), (u32)hh[2] | ((u32)hh[3] << 16)};
      *(uint2*)&aX[1][base] = {(u32)ll[0] | ((u32)ll[1] << 16), (u32)ll[2] | ((u32)ll[3] << 16)};
    }
    if constexpr (!FIRST) {
      const uint4* hr = (const uint4*)(Hnext + (size_t)i * 256);
      #pragma unroll
      for (int q = 0; q < 4; ++q) {
        uint4 u = hr[seg * 4 + q];
        int k0 = seg * 16 + q * 4;
        int base = ((k0 >> 3) * 32 + row) * 8 + (k0 & 7);
        u32 uu[4] = {u.x, u.y, u.z, u.w};
        *(uint2*)&aH[0][base] = {(uu[0] & 0xffffu) | ((uu[1] & 0xffffu) << 16),
                                 (uu[2] & 0xffffu) | ((uu[3] & 0xffffu) << 16)};
        *(uint2*)&aH[1][base] = {(uu[0] >> 16) | (uu[1] & 0xffff0000u),
                                 (uu[2] >> 16) | (uu[3] & 0xffff0000u)};
      }
    }
  }
  __syncthreads();

  const int lane = t & 63, w = t >> 6;
  const int asub = lane >> 4;
  const int l15 = lane & 15;

  f4 gi[3][2][2], gh[3][2][2], sa[2][2];
  #pragma unroll
  for (int g = 0; g < 3; ++g)
    #pragma unroll
    for (int jc = 0; jc < 2; ++jc)
      #pragma unroll
      for (int mf = 0; mf < 2; ++mf) {
        gi[g][jc][mf] = (f4){0.f, 0.f, 0.f, 0.f};
        if constexpr (!FIRST) gh[g][jc][mf] = (f4){0.f, 0.f, 0.f, 0.f};
      }
  if constexpr (!FIRST) {
    #pragma unroll
    for (int jc = 0; jc < 2; ++jc)
      #pragma unroll
      for (int mf = 0; mf < 2; ++mf) sa[jc][mf] = (f4){0.f, 0.f, 0.f, 0.f};
  }

  #pragma unroll
  for (int kb = 0; kb < 8; ++kb) {
    s8 axh[2], axl[2], ahh[2], ahl[2];
    #pragma unroll
    for (int mf = 0; mf < 2; ++mf) {
      int abase = ((kb * 4 + asub) * 32 + 16 * mf + l15) * 8;
      axh[mf] = *(const s8*)&aX[0][abase];
      axl[mf] = *(const s8*)&aX[1][abase];
      if constexpr (!FIRST) {
        ahh[mf] = *(const s8*)&aH[0][abase];
        ahl[mf] = *(const s8*)&aH[1][abase];
      }
    }
    #pragma unroll
    for (int jc = 0; jc < 2; ++jc) {
      const int cf = 2 * w + jc;
      #pragma unroll
      for (int g = 0; g < 3; ++g) {
        size_t bo = ((size_t)(kb * 48 + 16 * g + cf) * 64 + lane) * 8;
        s8 b = *(const s8*)&wihP[bo];
        gi[g][jc][0] = MFMA16(axh[0], b, gi[g][jc][0]);
        gi[g][jc][1] = MFMA16(axh[1], b, gi[g][jc][1]);
        gi[g][jc][0] = MFMA16(axl[0], b, gi[g][jc][0]);
        gi[g][jc][1] = MFMA16(axl[1], b, gi[g][jc][1]);
        if constexpr (!FIRST) {
          s8 bh = *(const s8*)&whhPh[bo];
          s8 bl = *(const s8*)&whhPl[bo];
          gh[g][jc][0] = MFMA16(ahh[0], bh, gh[g][jc][0]);
          gh[g][jc][1] = MFMA16(ahh[1], bh, gh[g][jc][1]);
          gh[g][jc][0] = MFMA16(ahl[0], bh, gh[g][jc][0]);
          gh[g][jc][1] = MFMA16(ahl[1], bh, gh[g][jc][1]);
          gh[g][jc][0] = MFMA16(ahh[0], bl, gh[g][jc][0]);
          gh[g][jc][1] = MFMA16(ahh[1], bl, gh[g][jc][1]);
        }
      }
      if constexpr (!FIRST) {
        size_t so = ((size_t)(kb * 16 + cf) * 64 + lane) * 8;
        s8 bsw = *(const s8*)&swPh[so];
        sa[jc][0] = MFMA16(ahh[0], bsw, sa[jc][0]);
        sa[jc][1] = MFMA16(ahh[1], bsw, sa[jc][1]);
        sa[jc][0] = MFMA16(ahl[0], bsw, sa[jc][0]);
        sa[jc][1] = MFMA16(ahl[1], bsw, sa[jc][1]);
      }
    }
  }

  if constexpr (!FIRST) {
    float part[2][4] = {{0.f, 0.f, 0.f, 0.f}, {0.f, 0.f, 0.f, 0.f}};
    #pragma unroll
    for (int jc = 0; jc < 2; ++jc) {
      int k = 16 * (2 * w + jc) + l15;
      float sbk = sb[k], cwk = cw[k];
      #pragma unroll
      for (int mf = 0; mf < 2; ++mf)
        #pragma unroll
        for (int j = 0; j < 4; ++j) part[mf][j] += tanhf(sa[jc][mf][j] + sbk) * cwk;
    }
    #pragma unroll
    for (int mf = 0; mf < 2; ++mf)
      #pragma unroll
      for (int j = 0; j < 4; ++j) {
        part[mf][j] += __shfl_xor(part[mf][j], 1);
        part[mf][j] += __shfl_xor(part[mf][j], 2);
        part[mf][j] += __shfl_xor(part[mf][j], 4);
        part[mf][j] += __shfl_xor(part[mf][j], 8);
      }
    if (l15 == 0) {
      #pragma unroll
      for (int mf = 0; mf < 2; ++mf)
        #pragma unroll
        for (int j = 0; j < 4; ++j) pm[w][16 * mf + 4 * asub + j] = part[mf][j];
    }
    __syncthreads();
    if (t < 32) {
      float v = 0.f;
      #pragma unroll
      for (int q = 0; q < 8; ++q) v += pm[q][t];
      scl[t] = sigmoidf_(tanhf(v) - u0p[0] - logSm1);
    }
    __syncthreads();
  }

  #pragma unroll
  for (int jc = 0; jc < 2; ++jc) {
    const int col = 16 * (2 * w + jc) + l15;
    const float bi0 = bih[col], bi1 = bih[256 + col], bi2 = bih[512 + col];
    const float bh0 = bhh[col], bh1 = bhh[256 + col], bh2 = bhh[512 + col];
    #pragma unroll
    for (int mf = 0; mf < 2; ++mf) {
      const int r0 = 16 * mf + 4 * asub;
      float hmax = -1e30f;
      #pragma unroll
      for (int j = 0; j < 4; ++j) {
        const int row = r0 + j;
        const int i = i0 + row;
        float ir = gi[0][jc][mf][j] + bi0;
        float iz = gi[1][jc][mf][j] + bi1;
        float inn = gi[2][jc][mf][j] + bi2;
        float g0 = bh0, g1 = bh1, g2 = bh2, hp = 0.f;
        if constexpr (!FIRST) {
          float sc = scl[row];
          g0 += sc * gh[0][jc][mf][j];
          g1 += sc * gh[1][jc][mf][j];
          g2 += sc * gh[2][jc][mf][j];
          int hidx = ((col >> 3) * 32 + row) * 8 + (col & 7);
          hp = sc * (bf2f(aH[0][hidx]) + bf2f(aH[1][hidx]));
        }
        float r = sigmoidf_(ir + g0);
        float z = sigmoidf_(iz + g1);
        float n = tanhf(inn + r * g2);
        float h = (1.f - z) * n + z * hp;
        if (store_mode == 1) {
          Hout[(size_t)i * 256 + col] = packh(h);
        } else if (store_mode == 2 && ((i & 3) == 3)) {
          Hout[(size_t)(i >> 2) * 256 + col] = packh(h);
        }
        if (bshift >= 2) {
          hmax = (j == 0) ? h : fmaxf(hmax, h);
        } else {
          atomicMax(outI + (size_t)i * 256 + col, __float_as_int(h));
        }
      }
      if (bshift >= 2) {
        atomicMax(outI + (size_t)((i0 + r0) >> bshift) * 256 + col, __float_as_int(hmax));
      }
    }
  }
}

// ---- tail kernel (levels 3,2,1,0): col-split + register-dbuf B loads ----
// grid = nrb*4. Block (rb = bid>>2, cb = bid&3): rows rb*32..+32, gate cols
// [64cb, 64cb+64). Wave w: cfl = w&3 (16-col frag), mf = w>>2. Attention
// replicated per block; wave w: sa col-frags 4*(w&3)+c (c=0..3), own mf only.
struct Bregs {
  s8 wi[3], wh[3], wl[3], sw[4];
};
template <bool ROOT>
__device__ __forceinline__ void loadB(int kb, int cf, int wq, int lane,
                                      const u16* __restrict__ wihP,
                                      const u16* __restrict__ whhPh,
                                      const u16* __restrict__ whhPl,
                                      const u16* __restrict__ swPh, Bregs& r) {
  #pragma unroll
  for (int g = 0; g < 3; ++g) {
    size_t bo = ((size_t)(kb * 48 + 16 * g + cf) * 64 + lane) * 8;
    r.wi[g] = *(const s8*)&wihP[bo];
    r.wh[g] = *(const s8*)&whhPh[bo];
    r.wl[g] = *(const s8*)&whhPl[bo];
  }
  #pragma unroll
  for (int c = 0; c < 4; ++c) {
    size_t so = ((size_t)(kb * 16 + 4 * wq + c) * 64 + lane) * 8;
    r.sw[c] = *(const s8*)&swPh[so];
  }
}

template <bool ROOT>
__global__ __launch_bounds__(512, 2)
void tail_kernel(const int* __restrict__ tokens, const float* __restrict__ emb,
                 const u16* __restrict__ wihP, const u16* __restrict__ whhPh,
                 const u16* __restrict__ whhPl, const u16* __restrict__ swPh,
                 const float* __restrict__ bih, const float* __restrict__ bhh,
                 const float* __restrict__ sb, const float* __restrict__ cw,
                 const float* __restrict__ u0p,
                 const u32* __restrict__ Hnext, u32* __restrict__ Hout,
                 int* __restrict__ outI,
                 float logSm1, int bshift, int store_mode) {
  __shared__ u16 aX[2][8192];
  __shared__ u16 aH[2][8192];
  __shared__ float pm[8][32];
  __shared__ float scl[32];

  const int t = threadIdx.x;
  const int rb = blockIdx.x >> 2, cb = blockIdx.x & 3;
  const int i0 = rb * 32;

  {
    int row = t & 31, seg = t >> 5;
    int i = i0 + row;
    int tok = tokens[ROOT ? i : 4 * i + 3];
    const float4* xr = (const float4*)(emb + (size_t)tok * 256);
    const uint4* hr = (const uint4*)(Hnext + (size_t)i * 256);
    #pragma unroll
    for (int q = 0; q < 4; ++q) {
      float4 v = xr[seg * 4 + q];
      uint4 u = hr[seg * 4 + q];
      int k0 = seg * 16 + q * 4;
      int base = ((k0 >> 3) * 32 + row) * 8 + (k0 & 7);
      float vv[4] = {v.x, v.y, v.z, v.w};
      u16 hh[4], ll[4];
      #pragma unroll
      for (int e = 0; e < 4; ++e) { hh[e] = f2bf(vv[e]); ll[e] = f2bf(vv[e] - bf2f(hh[e])); }
      *(uint2*)&aX[0][base] = {(u32)hh[0] | ((u32)hh[1] << 16), (u32)hh[2] | ((u32)hh[3] << 16)};
      *(uint2*)&aX[1][base] = {(u32)ll[0] | ((u32)ll[1] << 16), (u32)ll[2] | ((u32)ll[3] << 16)};
      u32 uu[4] = {u.x, u.y, u.z, u.w};
      *(uint2*)&aH[0][base] = {(uu[0] & 0xffffu) | ((uu[1] & 0xffffu) << 16),
                               (uu[2] & 0xffffu) | ((uu[3] & 0xffffu) << 16)};
      *(uint2*)&aH[1][base] = {(uu[0] >> 16) | (uu[1] & 0xffff0000u),
                               (uu[2] >> 16) | (uu[3] & 0xffff0000u)};
    }
  }
  __syncthreads();

  const int lane = t & 63, w = t >> 6;
  const int wq = w & 3, mf = w >> 2;
  const int asub = lane >> 4;
  const int l15 = lane & 15;
  const int cf = 4 * cb + wq;

  f4 gi[3], gh[3], sa[4];
  #pragma unroll
  for (int g = 0; g < 3; ++g) { gi[g] = (f4){0.f, 0.f, 0.f, 0.f}; gh[g] = (f4){0.f, 0.f, 0.f, 0.f}; }
  #pragma unroll
  for (int c = 0; c < 4; ++c) sa[c] = (f4){0.f, 0.f, 0.f, 0.f};

  Bregs b0, b1;
  loadB<ROOT>(0, cf, wq, lane, wihP, whhPh, whhPl, swPh, b0);

  #pragma unroll
  for (int kb = 0; kb < 8; ++kb) {
    Bregs& cur = (kb & 1) ? b1 : b0;
    Bregs& nxt = (kb & 1) ? b0 : b1;
    if (kb < 7) loadB<ROOT>(kb + 1, cf, wq, lane, wihP, whhPh, whhPl, swPh, nxt);
    int abase = ((kb * 4 + asub) * 32 + 16 * mf + l15) * 8;
    s8 axh = *(const s8*)&aX[0][abase];
    s8 axl = *(const s8*)&aX[1][abase];
    s8 ahh = *(const s8*)&aH[0][abase];
    s8 ahl = *(const s8*)&aH[1][abase];
    #pragma unroll
    for (int g = 0; g < 3; ++g) {
      gi[g] = MFMA16(axh, cur.wi[g], gi[g]);
      gi[g] = MFMA16(axl, cur.wi[g], gi[g]);
      gh[g] = MFMA16(ahh, cur.wh[g], gh[g]);
      gh[g] = MFMA16(ahl, cur.wh[g], gh[g]);
      gh[g] = MFMA16(ahh, cur.wl[g], gh[g]);
    }
    #pragma unroll
    for (int c = 0; c < 4; ++c) {
      sa[c] = MFMA16(ahh, cur.sw[c], sa[c]);
      sa[c] = MFMA16(ahl, cur.sw[c], sa[c]);
    }
  }

  // attention partial: wave covers k-cols [64*wq, 64*wq+64) for own-mf rows
  {
    float part[4] = {0.f, 0.f, 0.f, 0.f};
    #pragma unroll
    for (int c = 0; c < 4; ++c) {
      int k = 16 * (4 * wq + c) + l15;
      float sbk = sb[k], cwk = cw[k];
      #pragma unroll
      for (int j = 0; j < 4; ++j) part[j] += tanhf(sa[c][j] + sbk) * cwk;
    }
    #pragma unroll
    for (int j = 0; j < 4; ++j) {
      part[j] += __shfl_xor(part[j], 1);
      part[j] += __shfl_xor(part[j], 2);
      part[j] += __shfl_xor(part[j], 4);
      part[j] += __shfl_xor(part[j], 8);
    }
    if (l15 == 0) {
      #pragma unroll
      for (int j = 0; j < 4; ++j) pm[w][16 * mf + 4 * asub + j] = part[j];
    }
    __syncthreads();
    if (t < 32) {
      int q0 = (t >> 4) * 4;  // waves holding this row's mf
      float v = pm[q0][t] + pm[q0 + 1][t] + pm[q0 + 2][t] + pm[q0 + 3][t];
      scl[t] = sigmoidf_(tanhf(v) - u0p[0] - logSm1);
    }
    __syncthreads();
  }

  // gates + store + fused max (wave's 16 cols x 16 rows)
  {
    const int col = 16 * cf + l15;
    const float bi0 = bih[col], bi1 = bih[256 + col], bi2 = bih[512 + col];
    const float bh0 = bhh[col], bh1 = bhh[256 + col], bh2 = bhh[512 + col];
    const int r0 = 16 * mf + 4 * asub;
    float hmax = -1e30f;
    #pragma unroll
    for (int j = 0; j < 4; ++j) {
      const int row = r0 + j;
      const int i = i0 + row;
      float sc = scl[row];
      float ir = gi[0][j] + bi0;
      float iz = gi[1][j] + bi1;
      float inn = gi[2][j] + bi2;
      float g0 = bh0 + sc * gh[0][j];
      float g1 = bh1 + sc * gh[1][j];
      float g2 = bh2 + sc * gh[2][j];
      int hidx = ((col >> 3) * 32 + row) * 8 + (col & 7);
      float hp = sc * (bf2f(aH[0][hidx]) + bf2f(aH[1][hidx]));
      float r = sigmoidf_(ir + g0);
      float z = sigmoidf_(iz + g1);
      float n = tanhf(inn + r * g2);
      float h = (1.f - z) * n + z * hp;
      if (store_mode == 1) {
        Hout[(size_t)i * 256 + col] = packh(h);
      } else if (store_mode == 2 && ((i & 3) == 3)) {
        Hout[(size_t)(i >> 2) * 256 + col] = packh(h);
      }
      if (bshift >= 2) {
        hmax = (j == 0) ? h : fmaxf(hmax, h);
      } else {
        atomicMax(outI + (size_t)i * 256 + col, __float_as_int(h));
      }
    }
    if (bshift >= 2) {
      atomicMax(outI + (size_t)((i0 + r0) >> bshift) * 256 + col, __float_as_int(hmax));
    }
  }
}

extern "C" void kernel_launch(void* const* d_in, const int* in_sizes, int n_in,
                              void* d_out, int out_size, void* d_ws, size_t ws_size,
                              hipStream_t stream) {
  const int*   tokens = (const int*)d_in[0];
  const float* emb    = (const float*)d_in[1];
  const float* wih    = (const float*)d_in[2];
  const float* whh    = (const float*)d_in[3];
  const float* bih    = (const float*)d_in[4];
  const float* bhh    = (const float*)d_in[5];
  const float* sw     = (const float*)d_in[6];
  const float* sb     = (const float*)d_in[7];
  const float* cw     = (const float*)d_in[8];

  char* ws = (char*)d_ws;
  u16* wihP  = (u16*)ws;                       // 196608 u16
  u16* whhPh = wihP + 196608;
  u16* whhPl = whhPh + 196608;
  u16* swPh  = whhPl + 196608;                 // 65536
  float* u0p = (float*)(ws + 1441792);         // 64 floats
  u32* Hs6 = (u32*)(ws + 1442048);             // 8192*256
  u32* Hs5 = Hs6 + 8192 * 256;                 // 2048*256
  u32* Hs4 = Hs5 + 2048 * 256;                 // 512*256
  u32* Hs3 = Hs4 + 512 * 256;                  // 128*256
  u32* Hs2 = Hs3 + 128 * 256;                  // 32*256
  u32* H1  = Hs2 + 32 * 256;                   // 32*256

  int* outI = (int*)d_out;
  hipMemsetAsync(d_out, 0, 32 * 256 * sizeof(float), stream);
  prep_pack<<<320, 256, 0, stream>>>(wih, whh, sw, wihP, whhPh, whhPl, swPh);
  u0_kernel<<<1, 64, 0, stream>>>(sb, cw, u0p);

  const float LN3  = 1.0986122886681098f;   // ln(A-1)
  const float LN31 = 3.4339872044851463f;   // ln(BS-1)

  // big levels
  level_kernel<true, false><<<1024, 512, 0, stream>>>(
      tokens + 43680, emb, wihP, whhPh, whhPl, swPh, bih, bhh, sb, cw, u0p,
      nullptr, Hs6, outI, 0.f, 10, 2);
  level_kernel<false, false><<<256, 512, 0, stream>>>(
      tokens + 10912, emb, wihP, whhPh, whhPl, swPh, bih, bhh, sb, cw, u0p,
      Hs6, Hs5, outI, LN3, 8, 2);
  level_kernel<false, false><<<64, 512, 0, stream>>>(
      tokens + 2720, emb, wihP, whhPh, whhPl, swPh, bih, bhh, sb, cw, u0p,
      Hs5, Hs4, outI, LN3, 6, 2);
  // tail levels (col-split x4)
  tail_kernel<false><<<64, 512, 0, stream>>>(
      tokens + 672, emb, wihP, whhPh, whhPl, swPh, bih, bhh, sb, cw, u0p,
      Hs4, Hs3, outI, LN3, 4, 2);
  tail_kernel<false><<<16, 512, 0, stream>>>(
      tokens + 160, emb, wihP, whhPh, whhPl, swPh, bih, bhh, sb, cw, u0p,
      Hs3, Hs2, outI, LN3, 2, 2);
  tail_kernel<false><<<4, 512, 0, stream>>>(
      tokens + 32, emb, wihP, whhPh, whhPl, swPh, bih, bhh, sb, cw, u0p,
      Hs2, H1, outI, LN3, 0, 1);
  tail_kernel<true><<<4, 512, 0, stream>>>(
      tokens + 0, emb, wihP, whhPh, whhPl, swPh, bih, bhh, sb, cw, u0p,
      H1, nullptr, outI, LN31, 0, 0);
}

// Round 5
// 198.509 us; speedup vs baseline: 4.9720x; 1.2940x over previous
//
#include <hip/hip_runtime.h>
#include <hip/hip_bf16.h>
#include <math.h>

// BatchTreeEncoder: BS=32, A=4, D=6, H=E=256, V=50000
// Compact rows (j%4==3) only; per-row attention scale (diagonal identity);
// fused atomicMax epilogue. MFMA bf16 split-precision GEMMs:
//   gi  = x_hi @ Wih_hi                          (1-term; err ~1e-4)
//   gh  = (h_hi+h_lo)@Whh_hi + h_hi@Whh_lo       (3-term)
//   hsw = (h_hi+h_lo)@SW_hi                      (2-term)
// All K-loops use explicit register double-buffering of B fragments (proven
// fix for load-latency stalls, round 3->4). levelA = L6 (h=0), CS=1.
// levelB = L5/L4, col-split x2 (wave: 1 col-frag x both m-frags).
// tail = L3..L0, col-split x4 (wave: 1 col-frag x 1 m-frag).

typedef unsigned short u16;
typedef unsigned int u32;
typedef __attribute__((ext_vector_type(8))) short s8;   // bf16x8 operand (4 VGPR)
typedef __attribute__((ext_vector_type(4))) float f4;   // fp32x4 acc
#define MFMA16(a, b, c) __builtin_amdgcn_mfma_f32_16x16x32_bf16(a, b, c, 0, 0, 0)

__device__ __forceinline__ u16 f2bf(float f) {
  u32 x = __float_as_uint(f);
  return (u16)((x + 0x7fffu + ((x >> 16) & 1u)) >> 16);
}
__device__ __forceinline__ float bf2f(u16 u) { return __uint_as_float(((u32)u) << 16); }
__device__ __forceinline__ float sigmoidf_(float x) { return 1.0f / (1.0f + expf(-x)); }
__device__ __forceinline__ u32 packh(float h) {
  u16 hi = f2bf(h);
  u16 lo = f2bf(h - bf2f(hi));
  return (u32)hi | ((u32)lo << 16);
}

// ---- pack weights into MFMA B-frag layout (hi / lo planes); block 320 = u0 ----
__global__ void prep_pack(const float* __restrict__ wih, const float* __restrict__ whh,
                          const float* __restrict__ sw,
                          const float* __restrict__ sb, const float* __restrict__ cw,
                          u16* __restrict__ wihP, u16* __restrict__ whhPh,
                          u16* __restrict__ whhPl, u16* __restrict__ swPh,
                          float* __restrict__ u0p) {
  int g = blockIdx.x * 256 + threadIdx.x;   // 0..81919 pack, block 320 = u0
  if (g >= 81920) {
    int lane = threadIdx.x;
    if (lane < 64) {
      float s = 0.f;
      #pragma unroll
      for (int q = 0; q < 4; ++q) { int k = lane + 64 * q; s += tanhf(sb[k]) * cw[k]; }
      #pragma unroll
      for (int off = 32; off >= 1; off >>= 1) s += __shfl_xor(s, off);
      if (lane == 0) u0p[0] = tanhf(s);
    }
    return;
  }
  const float* src;
  u16* dst;
  int idx, NF, lomode, trans;
  if (g < 24576)      { idx = g;         src = wih; dst = wihP;  NF = 48; lomode = 0; trans = 1; }
  else if (g < 49152) { idx = g - 24576; src = whh; dst = whhPh; NF = 48; lomode = 0; trans = 1; }
  else if (g < 73728) { idx = g - 49152; src = whh; dst = whhPl; NF = 48; lomode = 1; trans = 1; }
  else                { idx = g - 73728; src = sw;  dst = swPh;  NF = 16; lomode = 0; trans = 0; }
  int lane = idx & 63;
  int t2 = idx >> 6;
  int nf = t2 % NF, kb = t2 / NF;
  int n = nf * 16 + (lane & 15);
  int k0 = kb * 32 + (lane >> 4) * 8;
  float v[8];
  if (trans) {
    const float4* p = (const float4*)(src + (size_t)n * 256 + k0);
    float4 a = p[0], b = p[1];
    v[0] = a.x; v[1] = a.y; v[2] = a.z; v[3] = a.w;
    v[4] = b.x; v[5] = b.y; v[6] = b.z; v[7] = b.w;
  } else {
    #pragma unroll
    for (int j = 0; j < 8; ++j) v[j] = src[(size_t)(k0 + j) * 256 + n];
  }
  u16 o[8];
  #pragma unroll
  for (int j = 0; j < 8; ++j) {
    u16 hi = f2bf(v[j]);
    o[j] = lomode ? f2bf(v[j] - bf2f(hi)) : hi;
  }
  u32* d = (u32*)(dst + (size_t)idx * 8);
  #pragma unroll
  for (int j = 0; j < 4; ++j) d[j] = (u32)o[2 * j] | ((u32)o[2 * j + 1] << 16);
}

// ---- levelA: L6 (FIRST, h=0). 32 rows/block, wave w: col-frags {2w,2w+1} x both mf.
__global__ __launch_bounds__(512, 4)
void levelA_kernel(const int* __restrict__ tokens, const float* __restrict__ emb,
                   const u16* __restrict__ wihP, const float* __restrict__ bih,
                   const float* __restrict__ bhh, u32* __restrict__ Hout,
                   int* __restrict__ outI) {
  __shared__ u16 aX[8192];
  const int t = threadIdx.x;
  const int i0 = blockIdx.x * 32;
  {
    int row = t & 31, seg = t >> 5;
    int tok = tokens[4 * (i0 + row) + 3];
    const float4* xr = (const float4*)(emb + (size_t)tok * 256);
    #pragma unroll
    for (int q = 0; q < 4; ++q) {
      float4 v = xr[seg * 4 + q];
      int k0 = seg * 16 + q * 4;
      int base = ((k0 >> 3) * 32 + row) * 8 + (k0 & 7);
      u16 h0 = f2bf(v.x), h1 = f2bf(v.y), h2 = f2bf(v.z), h3 = f2bf(v.w);
      *(uint2*)&aX[base] = {(u32)h0 | ((u32)h1 << 16), (u32)h2 | ((u32)h3 << 16)};
    }
  }
  __syncthreads();
  const int lane = t & 63, w = t >> 6;
  const int asub = lane >> 4, l15 = lane & 15;

  f4 gi[3][2][2];   // [g][jc][mf]
  #pragma unroll
  for (int g = 0; g < 3; ++g)
    #pragma unroll
    for (int jc = 0; jc < 2; ++jc)
      #pragma unroll
      for (int mf = 0; mf < 2; ++mf) gi[g][jc][mf] = (f4){0.f, 0.f, 0.f, 0.f};

  s8 bw[2][2][3];   // [pb][jc][g]
  auto LB = [&](int kb, int pb) {
    #pragma unroll
    for (int jc = 0; jc < 2; ++jc)
      #pragma unroll
      for (int g = 0; g < 3; ++g) {
        size_t bo = ((size_t)(kb * 48 + 16 * g + 2 * w + jc) * 64 + lane) * 8;
        bw[pb][jc][g] = *(const s8*)&wihP[bo];
      }
  };
  LB(0, 0);
  #pragma unroll
  for (int kb = 0; kb < 8; ++kb) {
    const int pb = kb & 1;
    if (kb < 7) LB(kb + 1, pb ^ 1);
    s8 axh[2];
    #pragma unroll
    for (int mf = 0; mf < 2; ++mf) {
      int abase = ((kb * 4 + asub) * 32 + 16 * mf + l15) * 8;
      axh[mf] = *(const s8*)&aX[abase];
    }
    #pragma unroll
    for (int jc = 0; jc < 2; ++jc)
      #pragma unroll
      for (int g = 0; g < 3; ++g) {
        gi[g][jc][0] = MFMA16(axh[0], bw[pb][jc][g], gi[g][jc][0]);
        gi[g][jc][1] = MFMA16(axh[1], bw[pb][jc][g], gi[g][jc][1]);
      }
  }

  #pragma unroll
  for (int jc = 0; jc < 2; ++jc) {
    const int col = 16 * (2 * w + jc) + l15;
    const float bi0 = bih[col], bi1 = bih[256 + col], bi2 = bih[512 + col];
    const float bh0 = bhh[col], bh1 = bhh[256 + col], bh2 = bhh[512 + col];
    #pragma unroll
    for (int mf = 0; mf < 2; ++mf) {
      const int r0 = 16 * mf + 4 * asub;
      float hmax = -1e30f;
      #pragma unroll
      for (int j = 0; j < 4; ++j) {
        const int i = i0 + r0 + j;
        float r = sigmoidf_(gi[0][jc][mf][j] + bi0 + bh0);
        float z = sigmoidf_(gi[1][jc][mf][j] + bi1 + bh1);
        float n = tanhf(gi[2][jc][mf][j] + bi2 + r * bh2);
        float h = (1.f - z) * n;
        if ((i & 3) == 3) Hout[(size_t)(i >> 2) * 256 + col] = packh(h);
        hmax = (j == 0) ? h : fmaxf(hmax, h);
      }
      atomicMax(outI + (size_t)((i0 + r0) >> 10) * 256 + col, __float_as_int(hmax));
    }
  }
}

// ---- levelB: L5/L4. col-split x2; wave w: gate col-frag 8*cb+w, both mf;
// attention sw frags {2w,2w+1}. Register-dbuf of 11 B frags per kb.
__global__ __launch_bounds__(512, 2)
void levelB_kernel(const int* __restrict__ tokens, const float* __restrict__ emb,
                   const u16* __restrict__ wihP, const u16* __restrict__ whhPh,
                   const u16* __restrict__ whhPl, const u16* __restrict__ swPh,
                   const float* __restrict__ bih, const float* __restrict__ bhh,
                   const float* __restrict__ sb, const float* __restrict__ cw,
                   const float* __restrict__ u0p,
                   const u32* __restrict__ Hnext, u32* __restrict__ Hout,
                   int* __restrict__ outI, float logSm1, int bshift) {
  __shared__ u16 aX[8192];
  __shared__ u16 aH[2][8192];
  __shared__ float pm[8][32];
  __shared__ float scl[32];

  const int t = threadIdx.x;
  const int rb = blockIdx.x >> 1, cb = blockIdx.x & 1;
  const int i0 = rb * 32;

  {
    int row = t & 31, seg = t >> 5;
    int i = i0 + row;
    int tok = tokens[4 * i + 3];
    const float4* xr = (const float4*)(emb + (size_t)tok * 256);
    const uint4* hr = (const uint4*)(Hnext + (size_t)i * 256);
    #pragma unroll
    for (int q = 0; q < 4; ++q) {
      float4 v = xr[seg * 4 + q];
      uint4 u = hr[seg * 4 + q];
      int k0 = seg * 16 + q * 4;
      int base = ((k0 >> 3) * 32 + row) * 8 + (k0 & 7);
      u16 h0 = f2bf(v.x), h1 = f2bf(v.y), h2 = f2bf(v.z), h3 = f2bf(v.w);
      *(uint2*)&aX[base] = {(u32)h0 | ((u32)h1 << 16), (u32)h2 | ((u32)h3 << 16)};
      u32 uu[4] = {u.x, u.y, u.z, u.w};
      *(uint2*)&aH[0][base] = {(uu[0] & 0xffffu) | ((uu[1] & 0xffffu) << 16),
                               (uu[2] & 0xffffu) | ((uu[3] & 0xffffu) << 16)};
      *(uint2*)&aH[1][base] = {(uu[0] >> 16) | (uu[1] & 0xffff0000u),
                               (uu[2] >> 16) | (uu[3] & 0xffff0000u)};
    }
  }
  __syncthreads();

  const int lane = t & 63, w = t >> 6;
  const int asub = lane >> 4, l15 = lane & 15;
  const int cfg = 8 * cb + w;

  f4 gi[3][2], gh[3][2], sa[2][2];  // [g][mf], [jc][mf]
  #pragma unroll
  for (int g = 0; g < 3; ++g)
    #pragma unroll
    for (int mf = 0; mf < 2; ++mf) {
      gi[g][mf] = (f4){0.f, 0.f, 0.f, 0.f};
      gh[g][mf] = (f4){0.f, 0.f, 0.f, 0.f};
    }
  #pragma unroll
  for (int jc = 0; jc < 2; ++jc)
    #pragma unroll
    for (int mf = 0; mf < 2; ++mf) sa[jc][mf] = (f4){0.f, 0.f, 0.f, 0.f};

  s8 bwi[2][3], bwh[2][3], bwl[2][3], bsw[2][2];
  auto LB = [&](int kb, int pb) {
    #pragma unroll
    for (int g = 0; g < 3; ++g) {
      size_t bo = ((size_t)(kb * 48 + 16 * g + cfg) * 64 + lane) * 8;
      bwi[pb][g] = *(const s8*)&wihP[bo];
      bwh[pb][g] = *(const s8*)&whhPh[bo];
      bwl[pb][g] = *(const s8*)&whhPl[bo];
    }
    #pragma unroll
    for (int jc = 0; jc < 2; ++jc) {
      size_t so = ((size_t)(kb * 16 + 2 * w + jc) * 64 + lane) * 8;
      bsw[pb][jc] = *(const s8*)&swPh[so];
    }
  };
  LB(0, 0);
  #pragma unroll
  for (int kb = 0; kb < 8; ++kb) {
    const int pb = kb & 1;
    if (kb < 7) LB(kb + 1, pb ^ 1);
    s8 axh[2], ahh[2], ahl[2];
    #pragma unroll
    for (int mf = 0; mf < 2; ++mf) {
      int abase = ((kb * 4 + asub) * 32 + 16 * mf + l15) * 8;
      axh[mf] = *(const s8*)&aX[abase];
      ahh[mf] = *(const s8*)&aH[0][abase];
      ahl[mf] = *(const s8*)&aH[1][abase];
    }
    #pragma unroll
    for (int g = 0; g < 3; ++g) {
      gi[g][0] = MFMA16(axh[0], bwi[pb][g], gi[g][0]);
      gi[g][1] = MFMA16(axh[1], bwi[pb][g], gi[g][1]);
      gh[g][0] = MFMA16(ahh[0], bwh[pb][g], gh[g][0]);
      gh[g][1] = MFMA16(ahh[1], bwh[pb][g], gh[g][1]);
      gh[g][0] = MFMA16(ahl[0], bwh[pb][g], gh[g][0]);
      gh[g][1] = MFMA16(ahl[1], bwh[pb][g], gh[g][1]);
      gh[g][0] = MFMA16(ahh[0], bwl[pb][g], gh[g][0]);
      gh[g][1] = MFMA16(ahh[1], bwl[pb][g], gh[g][1]);
    }
    #pragma unroll
    for (int jc = 0; jc < 2; ++jc) {
      sa[jc][0] = MFMA16(ahh[0], bsw[pb][jc], sa[jc][0]);
      sa[jc][1] = MFMA16(ahh[1], bsw[pb][jc], sa[jc][1]);
      sa[jc][0] = MFMA16(ahl[0], bsw[pb][jc], sa[jc][0]);
      sa[jc][1] = MFMA16(ahl[1], bsw[pb][jc], sa[jc][1]);
    }
  }

  // attention scale
  {
    float part[2][4] = {{0.f, 0.f, 0.f, 0.f}, {0.f, 0.f, 0.f, 0.f}};
    #pragma unroll
    for (int jc = 0; jc < 2; ++jc) {
      int k = 16 * (2 * w + jc) + l15;
      float sbk = sb[k], cwk = cw[k];
      #pragma unroll
      for (int mf = 0; mf < 2; ++mf)
        #pragma unroll
        for (int j = 0; j < 4; ++j) part[mf][j] += tanhf(sa[jc][mf][j] + sbk) * cwk;
    }
    #pragma unroll
    for (int mf = 0; mf < 2; ++mf)
      #pragma unroll
      for (int j = 0; j < 4; ++j) {
        part[mf][j] += __shfl_xor(part[mf][j], 1);
        part[mf][j] += __shfl_xor(part[mf][j], 2);
        part[mf][j] += __shfl_xor(part[mf][j], 4);
        part[mf][j] += __shfl_xor(part[mf][j], 8);
      }
    if (l15 == 0) {
      #pragma unroll
      for (int mf = 0; mf < 2; ++mf)
        #pragma unroll
        for (int j = 0; j < 4; ++j) pm[w][16 * mf + 4 * asub + j] = part[mf][j];
    }
    __syncthreads();
    if (t < 32) {
      float v = 0.f;
      #pragma unroll
      for (int q = 0; q < 8; ++q) v += pm[q][t];
      scl[t] = sigmoidf_(tanhf(v) - u0p[0] - logSm1);
    }
    __syncthreads();
  }

  // gates + compact store + fused max
  {
    const int col = 16 * cfg + l15;
    const float bi0 = bih[col], bi1 = bih[256 + col], bi2 = bih[512 + col];
    const float bh0 = bhh[col], bh1 = bhh[256 + col], bh2 = bhh[512 + col];
    #pragma unroll
    for (int mf = 0; mf < 2; ++mf) {
      const int r0 = 16 * mf + 4 * asub;
      float hmax = -1e30f;
      #pragma unroll
      for (int j = 0; j < 4; ++j) {
        const int row = r0 + j;
        const int i = i0 + row;
        float sc = scl[row];
        float ir = gi[0][mf][j] + bi0;
        float iz = gi[1][mf][j] + bi1;
        float inn = gi[2][mf][j] + bi2;
        float g0 = bh0 + sc * gh[0][mf][j];
        float g1 = bh1 + sc * gh[1][mf][j];
        float g2 = bh2 + sc * gh[2][mf][j];
        int hidx = ((col >> 3) * 32 + row) * 8 + (col & 7);
        float hp = sc * (bf2f(aH[0][hidx]) + bf2f(aH[1][hidx]));
        float r = sigmoidf_(ir + g0);
        float z = sigmoidf_(iz + g1);
        float n = tanhf(inn + r * g2);
        float h = (1.f - z) * n + z * hp;
        if ((i & 3) == 3) Hout[(size_t)(i >> 2) * 256 + col] = packh(h);
        hmax = (j == 0) ? h : fmaxf(hmax, h);
      }
      atomicMax(outI + (size_t)((i0 + r0) >> bshift) * 256 + col, __float_as_int(hmax));
    }
  }
}

// ---- tail kernel (levels 3,2,1,0): col-split x4 + register-dbuf B loads ----
struct Bregs {
  s8 wi[3], wh[3], wl[3], sw[4];
};
__device__ __forceinline__ void loadB(int kb, int cf, int wq, int lane,
                                      const u16* __restrict__ wihP,
                                      const u16* __restrict__ whhPh,
                                      const u16* __restrict__ whhPl,
                                      const u16* __restrict__ swPh, Bregs& r) {
  #pragma unroll
  for (int g = 0; g < 3; ++g) {
    size_t bo = ((size_t)(kb * 48 + 16 * g + cf) * 64 + lane) * 8;
    r.wi[g] = *(const s8*)&wihP[bo];
    r.wh[g] = *(const s8*)&whhPh[bo];
    r.wl[g] = *(const s8*)&whhPl[bo];
  }
  #pragma unroll
  for (int c = 0; c < 4; ++c) {
    size_t so = ((size_t)(kb * 16 + 4 * wq + c) * 64 + lane) * 8;
    r.sw[c] = *(const s8*)&swPh[so];
  }
}

template <bool ROOT>
__global__ __launch_bounds__(512, 2)
void tail_kernel(const int* __restrict__ tokens, const float* __restrict__ emb,
                 const u16* __restrict__ wihP, const u16* __restrict__ whhPh,
                 const u16* __restrict__ whhPl, const u16* __restrict__ swPh,
                 const float* __restrict__ bih, const float* __restrict__ bhh,
                 const float* __restrict__ sb, const float* __restrict__ cw,
                 const float* __restrict__ u0p,
                 const u32* __restrict__ Hnext, u32* __restrict__ Hout,
                 int* __restrict__ outI,
                 float logSm1, int bshift, int store_mode) {
  __shared__ u16 aX[8192];
  __shared__ u16 aH[2][8192];
  __shared__ float pm[8][32];
  __shared__ float scl[32];

  const int t = threadIdx.x;
  const int rb = blockIdx.x >> 2, cb = blockIdx.x & 3;
  const int i0 = rb * 32;

  {
    int row = t & 31, seg = t >> 5;
    int i = i0 + row;
    int tok = tokens[ROOT ? i : 4 * i + 3];
    const float4* xr = (const float4*)(emb + (size_t)tok * 256);
    const uint4* hr = (const uint4*)(Hnext + (size_t)i * 256);
    #pragma unroll
    for (int q = 0; q < 4; ++q) {
      float4 v = xr[seg * 4 + q];
      uint4 u = hr[seg * 4 + q];
      int k0 = seg * 16 + q * 4;
      int base = ((k0 >> 3) * 32 + row) * 8 + (k0 & 7);
      u16 h0 = f2bf(v.x), h1 = f2bf(v.y), h2 = f2bf(v.z), h3 = f2bf(v.w);
      *(uint2*)&aX[base] = {(u32)h0 | ((u32)h1 << 16), (u32)h2 | ((u32)h3 << 16)};
      u32 uu[4] = {u.x, u.y, u.z, u.w};
      *(uint2*)&aH[0][base] = {(uu[0] & 0xffffu) | ((uu[1] & 0xffffu) << 16),
                               (uu[2] & 0xffffu) | ((uu[3] & 0xffffu) << 16)};
      *(uint2*)&aH[1][base] = {(uu[0] >> 16) | (uu[1] & 0xffff0000u),
                               (uu[2] >> 16) | (uu[3] & 0xffff0000u)};
    }
  }
  __syncthreads();

  const int lane = t & 63, w = t >> 6;
  const int wq = w & 3, mf = w >> 2;
  const int asub = lane >> 4;
  const int l15 = lane & 15;
  const int cf = 4 * cb + wq;

  f4 gi[3], gh[3], sa[4];
  #pragma unroll
  for (int g = 0; g < 3; ++g) { gi[g] = (f4){0.f, 0.f, 0.f, 0.f}; gh[g] = (f4){0.f, 0.f, 0.f, 0.f}; }
  #pragma unroll
  for (int c = 0; c < 4; ++c) sa[c] = (f4){0.f, 0.f, 0.f, 0.f};

  Bregs b0, b1;
  loadB(0, cf, wq, lane, wihP, whhPh, whhPl, swPh, b0);

  #pragma unroll
  for (int kb = 0; kb < 8; ++kb) {
    Bregs& cur = (kb & 1) ? b1 : b0;
    Bregs& nxt = (kb & 1) ? b0 : b1;
    if (kb < 7) loadB(kb + 1, cf, wq, lane, wihP, whhPh, whhPl, swPh, nxt);
    int abase = ((kb * 4 + asub) * 32 + 16 * mf + l15) * 8;
    s8 axh = *(const s8*)&aX[abase];
    s8 ahh = *(const s8*)&aH[0][abase];
    s8 ahl = *(const s8*)&aH[1][abase];
    #pragma unroll
    for (int g = 0; g < 3; ++g) {
      gi[g] = MFMA16(axh, cur.wi[g], gi[g]);
      gh[g] = MFMA16(ahh, cur.wh[g], gh[g]);
      gh[g] = MFMA16(ahl, cur.wh[g], gh[g]);
      gh[g] = MFMA16(ahh, cur.wl[g], gh[g]);
    }
    #pragma unroll
    for (int c = 0; c < 4; ++c) {
      sa[c] = MFMA16(ahh, cur.sw[c], sa[c]);
      sa[c] = MFMA16(ahl, cur.sw[c], sa[c]);
    }
  }

  // attention partial: wave covers k-cols [64*wq, 64*wq+64) for own-mf rows
  {
    float part[4] = {0.f, 0.f, 0.f, 0.f};
    #pragma unroll
    for (int c = 0; c < 4; ++c) {
      int k = 16 * (4 * wq + c) + l15;
      float sbk = sb[k], cwk = cw[k];
      #pragma unroll
      for (int j = 0; j < 4; ++j) part[j] += tanhf(sa[c][j] + sbk) * cwk;
    }
    #pragma unroll
    for (int j = 0; j < 4; ++j) {
      part[j] += __shfl_xor(part[j], 1);
      part[j] += __shfl_xor(part[j], 2);
      part[j] += __shfl_xor(part[j], 4);
      part[j] += __shfl_xor(part[j], 8);
    }
    if (l15 == 0) {
      #pragma unroll
      for (int j = 0; j < 4; ++j) pm[w][16 * mf + 4 * asub + j] = part[j];
    }
    __syncthreads();
    if (t < 32) {
      int q0 = (t >> 4) * 4;
      float v = pm[q0][t] + pm[q0 + 1][t] + pm[q0 + 2][t] + pm[q0 + 3][t];
      scl[t] = sigmoidf_(tanhf(v) - u0p[0] - logSm1);
    }
    __syncthreads();
  }

  // gates + store + fused max (wave's 16 cols x 16 rows)
  {
    const int col = 16 * cf + l15;
    const float bi0 = bih[col], bi1 = bih[256 + col], bi2 = bih[512 + col];
    const float bh0 = bhh[col], bh1 = bhh[256 + col], bh2 = bhh[512 + col];
    const int r0 = 16 * mf + 4 * asub;
    float hmax = -1e30f;
    #pragma unroll
    for (int j = 0; j < 4; ++j) {
      const int row = r0 + j;
      const int i = i0 + row;
      float sc = scl[row];
      float ir = gi[0][j] + bi0;
      float iz = gi[1][j] + bi1;
      float inn = gi[2][j] + bi2;
      float g0 = bh0 + sc * gh[0][j];
      float g1 = bh1 + sc * gh[1][j];
      float g2 = bh2 + sc * gh[2][j];
      int hidx = ((col >> 3) * 32 + row) * 8 + (col & 7);
      float hp = sc * (bf2f(aH[0][hidx]) + bf2f(aH[1][hidx]));
      float r = sigmoidf_(ir + g0);
      float z = sigmoidf_(iz + g1);
      float n = tanhf(inn + r * g2);
      float h = (1.f - z) * n + z * hp;
      if (store_mode == 1) {
        Hout[(size_t)i * 256 + col] = packh(h);
      } else if (store_mode == 2 && ((i & 3) == 3)) {
        Hout[(size_t)(i >> 2) * 256 + col] = packh(h);
      }
      if (bshift >= 2) {
        hmax = (j == 0) ? h : fmaxf(hmax, h);
      } else {
        atomicMax(outI + (size_t)i * 256 + col, __float_as_int(h));
      }
    }
    if (bshift >= 2) {
      atomicMax(outI + (size_t)((i0 + r0) >> bshift) * 256 + col, __float_as_int(hmax));
    }
  }
}

extern "C" void kernel_launch(void* const* d_in, const int* in_sizes, int n_in,
                              void* d_out, int out_size, void* d_ws, size_t ws_size,
                              hipStream_t stream) {
  const int*   tokens = (const int*)d_in[0];
  const float* emb    = (const float*)d_in[1];
  const float* wih    = (const float*)d_in[2];
  const float* whh    = (const float*)d_in[3];
  const float* bih    = (const float*)d_in[4];
  const float* bhh    = (const float*)d_in[5];
  const float* sw     = (const float*)d_in[6];
  const float* sb     = (const float*)d_in[7];
  const float* cw     = (const float*)d_in[8];

  char* ws = (char*)d_ws;
  u16* wihP  = (u16*)ws;                       // 196608 u16
  u16* whhPh = wihP + 196608;
  u16* whhPl = whhPh + 196608;
  u16* swPh  = whhPl + 196608;                 // 65536
  float* u0p = (float*)(ws + 1441792);         // 64 floats
  u32* Hs6 = (u32*)(ws + 1442048);             // 8192*256
  u32* Hs5 = Hs6 + 8192 * 256;                 // 2048*256
  u32* Hs4 = Hs5 + 2048 * 256;                 // 512*256
  u32* Hs3 = Hs4 + 512 * 256;                  // 128*256
  u32* Hs2 = Hs3 + 128 * 256;                  // 32*256
  u32* H1  = Hs2 + 32 * 256;                   // 32*256

  int* outI = (int*)d_out;
  hipMemsetAsync(d_out, 0, 32 * 256 * sizeof(float), stream);
  prep_pack<<<321, 256, 0, stream>>>(wih, whh, sw, sb, cw, wihP, whhPh, whhPl, swPh, u0p);

  const float LN3  = 1.0986122886681098f;   // ln(A-1)
  const float LN31 = 3.4339872044851463f;   // ln(BS-1)

  // L6 (FIRST)
  levelA_kernel<<<1024, 512, 0, stream>>>(tokens + 43680, emb, wihP, bih, bhh, Hs6, outI);
  // L5, L4 (col-split x2)
  levelB_kernel<<<512, 512, 0, stream>>>(
      tokens + 10912, emb, wihP, whhPh, whhPl, swPh, bih, bhh, sb, cw, u0p,
      Hs6, Hs5, outI, LN3, 8);
  levelB_kernel<<<128, 512, 0, stream>>>(
      tokens + 2720, emb, wihP, whhPh, whhPl, swPh, bih, bhh, sb, cw, u0p,
      Hs5, Hs4, outI, LN3, 6);
  // tail levels (col-split x4)
  tail_kernel<false><<<64, 512, 0, stream>>>(
      tokens + 672, emb, wihP, whhPh, whhPl, swPh, bih, bhh, sb, cw, u0p,
      Hs4, Hs3, outI, LN3, 4, 2);
  tail_kernel<false><<<16, 512, 0, stream>>>(
      tokens + 160, emb, wihP, whhPh, whhPl, swPh, bih, bhh, sb, cw, u0p,
      Hs3, Hs2, outI, LN3, 2, 2);
  tail_kernel<false><<<4, 512, 0, stream>>>(
      tokens + 32, emb, wihP, whhPh, whhPl, swPh, bih, bhh, sb, cw, u0p,
      Hs2, H1, outI, LN3, 0, 1);
  tail_kernel<true><<<4, 512, 0, stream>>>(
      tokens + 0, emb, wihP, whhPh, whhPl, swPh, bih, bhh, sb, cw, u0p,
      H1, nullptr, outI, LN31, 0, 0);
}